// Round 2
// baseline (3708.926 us; speedup 1.0000x reference)
//
#include <hip/hip_runtime.h>
#include <hip/hip_bf16.h>

#define N_NODES 20000
#define N_EDGES 100000
#define HID 512
#define G3 1536   // 3*HID
#define NH 8
#define OD 64

typedef __hip_bfloat16 bf16;

__device__ __forceinline__ float sigmoidf_(float x) { return 1.0f / (1.0f + __expf(-x)); }
__device__ __forceinline__ float b2f(bf16 b) { return __bfloat162float(b); }
__device__ __forceinline__ bf16 f2b(float f) { return __float2bfloat16(f); }
// order-preserving float<->uint for atomicMax-based segment max
__device__ __forceinline__ unsigned ford(float f) {
    unsigned u = __float_as_uint(f);
    return (u & 0x80000000u) ? ~u : (u | 0x80000000u);
}
__device__ __forceinline__ float iford(unsigned u) {
    return __uint_as_float((u & 0x80000000u) ? (u & 0x7fffffffu) : ~u);
}

// ---- K0: transpose W_hh [1536][512] -> WT [512][1536]; W_ih [1536][64] -> WIT [64][1536]
__global__ __launch_bounds__(256) void k_transpose(const float* __restrict__ Whh,
                                                   const float* __restrict__ Wih,
                                                   float* __restrict__ WT,
                                                   float* __restrict__ WIT) {
    int i = blockIdx.x * 256 + threadIdx.x;       // grid covers 786432 + 98304 exactly
    if (i < G3 * HID) {
        int j = i >> 9, k = i & 511;
        WT[(size_t)k * G3 + j] = Whh[i];
    } else {
        int t = i - G3 * HID;
        int j = t >> 6, d = t & 63;
        WIT[(size_t)d * G3 + j] = Wih[t];
    }
}

// ---- K1: G[n][j] = features[n] . W_ih[j] + b_ih[j]   (per-node gi table, all 3 gates)
// block: 16 nodes x 256 j (grid 1250 x 6)
__global__ __launch_bounds__(256) void k_gi(const float* __restrict__ feat,
                                            const float* __restrict__ WIT,
                                            const float* __restrict__ b_ih,
                                            bf16* __restrict__ G) {
    __shared__ float fs[16][64];
    const int n0 = blockIdx.x * 16;
    const int j = blockIdx.y * 256 + threadIdx.x;
    for (int i = threadIdx.x; i < 16 * 64; i += 256)
        fs[0][i] = feat[(size_t)n0 * 64 + i];
    __syncthreads();
    float acc[16];
    const float b = b_ih[j];
#pragma unroll
    for (int e = 0; e < 16; ++e) acc[e] = b;
    for (int d = 0; d < 64; d += 4) {
        float w0 = WIT[(size_t)(d + 0) * G3 + j];
        float w1 = WIT[(size_t)(d + 1) * G3 + j];
        float w2 = WIT[(size_t)(d + 2) * G3 + j];
        float w3 = WIT[(size_t)(d + 3) * G3 + j];
#pragma unroll
        for (int e = 0; e < 16; ++e) {
            float4 f = *(const float4*)&fs[e][d];
            acc[e] += w0 * f.x + w1 * f.y + w2 * f.z + w3 * f.w;
        }
    }
#pragma unroll
    for (int e = 0; e < 16; ++e)
        G[(size_t)(n0 + e) * G3 + j] = f2b(acc[e]);
}

// ---- K2: H1[n] = GRU step1 with h0=0 (gh = b_hh), per node, elementwise
__global__ __launch_bounds__(256) void k_h1(const bf16* __restrict__ G,
                                            const float* __restrict__ b_hh,
                                            bf16* __restrict__ H1) {
    int i = blockIdx.x * 256 + threadIdx.x;  // N*HID exactly
    int n = i >> 9, k = i & 511;
    const bf16* g = G + (size_t)n * G3;
    float r = sigmoidf_(b2f(g[k]) + b_hh[k]);
    float z = sigmoidf_(b2f(g[HID + k]) + b_hh[HID + k]);
    float ng = tanhf(b2f(g[2 * HID + k]) + r * b_hh[2 * HID + k]);
    H1[i] = f2b((1.0f - z) * ng);  // + z*h0 = 0
}

// ---- K3: GH2[n] = H1[n] @ W_hh^T + b_hh  (per-node gh for step 2)
// block: 16 nodes, 256 threads; thread owns j = jj*256+tid for jj in 0..5
__global__ __launch_bounds__(256) void k_gh2(const bf16* __restrict__ H1,
                                             const float* __restrict__ WT,
                                             const float* __restrict__ b_hh,
                                             bf16* __restrict__ GH2) {
    __shared__ float hs[16][HID];
    const int n0 = blockIdx.x * 16;
    const int tid = threadIdx.x;
    for (int i = tid; i < 16 * HID; i += 256)
        hs[0][i] = b2f(H1[(size_t)n0 * HID + i]);
    __syncthreads();
    float acc[6][16];
#pragma unroll
    for (int jj = 0; jj < 6; ++jj)
#pragma unroll
        for (int e = 0; e < 16; ++e) acc[jj][e] = 0.f;
    for (int k = 0; k < HID; k += 4) {
        float w[6][4];
#pragma unroll
        for (int u = 0; u < 4; ++u)
#pragma unroll
            for (int jj = 0; jj < 6; ++jj)
                w[jj][u] = WT[(size_t)(k + u) * G3 + jj * 256 + tid];  // lane-coalesced
#pragma unroll
        for (int e = 0; e < 16; ++e) {
            float4 h = *(const float4*)&hs[e][k];  // LDS broadcast
#pragma unroll
            for (int jj = 0; jj < 6; ++jj)
                acc[jj][e] += w[jj][0] * h.x + w[jj][1] * h.y + w[jj][2] * h.z + w[jj][3] * h.w;
        }
    }
#pragma unroll
    for (int jj = 0; jj < 6; ++jj) {
        float b = b_hh[jj * 256 + tid];
#pragma unroll
        for (int e = 0; e < 16; ++e)
            GH2[(size_t)(n0 + e) * G3 + jj * 256 + tid] = f2b(acc[jj][e] + b);
    }
}

// ---- K5: fused per-edge: h2 = GRUstep2(G[i1], GH2[i0], H1[i0]) (LDS);
//          gh3 = h2 @ W_hh^T (per-edge GEMM, the only per-edge matmul);
//          h3 = GRUstep3(G[i2], gh3+b_hh, h2) -> eft
// block: 16 edges, 256 threads
__global__ __launch_bounds__(256) void k_step3(const bf16* __restrict__ G,
                                               const bf16* __restrict__ GH2,
                                               const bf16* __restrict__ H1,
                                               const float* __restrict__ WT,
                                               const float* __restrict__ b_hh,
                                               const int* __restrict__ emi,
                                               bf16* __restrict__ eft) {
    __shared__ float hs[16][HID];
    __shared__ int si[16][3];
    const int e0 = blockIdx.x * 16;
    const int tid = threadIdx.x;
    if (tid < 48) si[0][tid] = emi[(size_t)e0 * 3 + tid];
    __syncthreads();
    // phase 1: h2 into LDS
    for (int i = tid; i < 16 * HID; i += 256) {
        int e = i >> 9, k = i & 511;
        int i0 = si[e][0], i1 = si[e][1];
        const bf16* g1 = G + (size_t)i1 * G3;
        const bf16* gh = GH2 + (size_t)i0 * G3;
        float r = sigmoidf_(b2f(g1[k]) + b2f(gh[k]));
        float z = sigmoidf_(b2f(g1[HID + k]) + b2f(gh[HID + k]));
        float ng = tanhf(b2f(g1[2 * HID + k]) + r * b2f(gh[2 * HID + k]));
        hs[e][k] = (1.0f - z) * ng + z * b2f(H1[(size_t)i0 * HID + k]);
    }
    __syncthreads();
    // phase 2: gh3 = h2 @ W_hh^T (acc[jj][e] for j = jj*256+tid)
    float acc[6][16];
#pragma unroll
    for (int jj = 0; jj < 6; ++jj)
#pragma unroll
        for (int e = 0; e < 16; ++e) acc[jj][e] = 0.f;
    for (int k = 0; k < HID; k += 4) {
        float w[6][4];
#pragma unroll
        for (int u = 0; u < 4; ++u)
#pragma unroll
            for (int jj = 0; jj < 6; ++jj)
                w[jj][u] = WT[(size_t)(k + u) * G3 + jj * 256 + tid];
#pragma unroll
        for (int e = 0; e < 16; ++e) {
            float4 h = *(const float4*)&hs[e][k];
#pragma unroll
            for (int jj = 0; jj < 6; ++jj)
                acc[jj][e] += w[jj][0] * h.x + w[jj][1] * h.y + w[jj][2] * h.z + w[jj][3] * h.w;
        }
    }
    // phase 3: gates for step 3; thread owns k = tid and k = 256+tid
    // j-ranges: r -> acc[0..1], z -> acc[2..3], n -> acc[4..5]
#pragma unroll
    for (int jj2 = 0; jj2 < 2; ++jj2) {
        const int k = jj2 * 256 + tid;
        const float br = b_hh[k], bz = b_hh[HID + k], bn = b_hh[2 * HID + k];
#pragma unroll
        for (int e = 0; e < 16; ++e) {
            int i2 = si[e][2];
            const bf16* g2 = G + (size_t)i2 * G3;
            float r = sigmoidf_(b2f(g2[k]) + acc[jj2][e] + br);
            float z = sigmoidf_(b2f(g2[HID + k]) + acc[2 + jj2][e] + bz);
            float ng = tanhf(b2f(g2[2 * HID + k]) + r * (acc[4 + jj2][e] + bn));
            eft[(size_t)(e0 + e) * HID + k] = f2b((1.0f - z) * ng + z * hs[e][k]);
        }
    }
}

// ---- K6: attention logits + leaky relu + segment max (atomic, ordered-uint)
__global__ __launch_bounds__(256) void k_logits(const bf16* __restrict__ eft,
                                                const float* __restrict__ attn,
                                                const int* __restrict__ dst,
                                                float* __restrict__ a,
                                                unsigned* __restrict__ amax) {
    int i = blockIdx.x * 256 + threadIdx.x;  // E*NH exactly
    int e = i >> 3, h = i & 7;
    const __hip_bfloat162* f2 = (const __hip_bfloat162*)(eft + (size_t)e * HID + h * OD);
    const float* at = attn + h * OD;
    float s = 0.f;
#pragma unroll
    for (int d = 0; d < OD / 2; ++d) {
        float2 fv = __bfloat1622float2(f2[d]);
        s += fv.x * at[2 * d] + fv.y * at[2 * d + 1];
    }
    s = (s >= 0.f) ? s : 0.01f * s;
    a[i] = s;
    atomicMax(&amax[(size_t)dst[e] * NH + h], ford(s));
}

// ---- K7: ea = exp(a - amax[dst]); denom += ea
__global__ __launch_bounds__(256) void k_ea(const int* __restrict__ dst,
                                            const unsigned* __restrict__ amax,
                                            float* __restrict__ a,
                                            float* __restrict__ denom) {
    int i = blockIdx.x * 256 + threadIdx.x;
    int e = i >> 3, h = i & 7;
    float m = iford(amax[(size_t)dst[e] * NH + h]);
    float v = __expf(a[i] - m);
    a[i] = v;
    atomicAdd(&denom[(size_t)dst[e] * NH + h], v);
}

// ---- K8: out[dst] += eft * (ea/denom)
__global__ __launch_bounds__(256) void k_agg(const bf16* __restrict__ eft,
                                             const float* __restrict__ a,
                                             const float* __restrict__ denom,
                                             const int* __restrict__ dst,
                                             float* __restrict__ out) {
    size_t i = (size_t)blockIdx.x * 256 + threadIdx.x;  // E*HID exactly
    int e = (int)(i >> 9), k = (int)(i & 511);
    int h = k >> 6;
    int dn = dst[e];
    float alpha = a[e * NH + h] / denom[(size_t)dn * NH + h];
    atomicAdd(&out[(size_t)dn * HID + k], b2f(eft[i]) * alpha);
}

extern "C" void kernel_launch(void* const* d_in, const int* in_sizes, int n_in,
                              void* d_out, int out_size, void* d_ws, size_t ws_size,
                              hipStream_t stream) {
    (void)in_sizes; (void)n_in; (void)ws_size;
    const float* feat = (const float*)d_in[0];
    const float* W_ih = (const float*)d_in[1];
    const float* W_hh = (const float*)d_in[2];
    const float* b_ih = (const float*)d_in[3];
    const float* b_hh = (const float*)d_in[4];
    const float* attn = (const float*)d_in[5];
    const int* emi = (const int*)d_in[6];
    const int* dst = (const int*)d_in[7];
    float* out = (float*)d_out;

    // workspace layout: bf16 big arrays; total ~242 MiB
    char* ws = (char*)d_ws;
    bf16* G = (bf16*)ws;                                   // N*1536 bf16
    bf16* GH2 = G + (size_t)N_NODES * G3;                  // N*1536 bf16
    bf16* H1 = GH2 + (size_t)N_NODES * G3;                 // N*512 bf16
    bf16* eft = H1 + (size_t)N_NODES * HID;                // E*512 bf16
    float* a = (float*)(eft + (size_t)N_EDGES * HID);      // E*8 f32 (logits, then ea)
    unsigned* amax = (unsigned*)(a + (size_t)N_EDGES * NH); // N*8 u32
    float* denom = (float*)(amax + (size_t)N_NODES * NH);  // N*8 f32
    float* WT = denom + (size_t)N_NODES * NH;              // 512*1536 f32
    float* WIT = WT + (size_t)HID * G3;                    // 64*1536 f32

    hipMemsetAsync(d_out, 0, (size_t)out_size * sizeof(float), stream);
    hipMemsetAsync(amax, 0, (size_t)2 * N_NODES * NH * sizeof(float), stream);  // amax+denom

    k_transpose<<<3456, 256, 0, stream>>>(W_hh, W_ih, WT, WIT);
    k_gi<<<dim3(1250, 6), 256, 0, stream>>>(feat, WIT, b_ih, G);
    k_h1<<<40000, 256, 0, stream>>>(G, b_hh, H1);
    k_gh2<<<1250, 256, 0, stream>>>(H1, WT, b_hh, GH2);
    k_step3<<<6250, 256, 0, stream>>>(G, GH2, H1, WT, b_hh, emi, eft);
    k_logits<<<3125, 256, 0, stream>>>(eft, attn, dst, a, amax);
    k_ea<<<3125, 256, 0, stream>>>(dst, amax, a, denom);
    k_agg<<<200000, 256, 0, stream>>>(eft, a, denom, dst, out);
}

// Round 5
// 1664.321 us; speedup vs baseline: 2.2285x; 2.2285x over previous
//
#include <hip/hip_runtime.h>
#include <hip/hip_bf16.h>

#define N_NODES 20000
#define N_EDGES 100000
#define HID 512
#define G3 1536   // 3*HID
#define NH 8
#define OD 64

typedef __hip_bfloat16 bf16;
typedef __attribute__((ext_vector_type(8))) short bf16x8;   // 8 bf16 = 4 VGPRs
typedef __attribute__((ext_vector_type(4))) float f32x4;

__device__ __forceinline__ float sigmoidf_(float x) { return 1.0f / (1.0f + __expf(-x)); }
__device__ __forceinline__ float b2f(bf16 b) { return __bfloat162float(b); }
__device__ __forceinline__ bf16 f2b(float f) { return __float2bfloat16(f); }
__device__ __forceinline__ float bs2f(short s) {
    return __uint_as_float(((unsigned)(unsigned short)s) << 16);
}
__device__ __forceinline__ short f2bs(float f) {
    bf16 b = __float2bfloat16(f);
    return *reinterpret_cast<short*>(&b);
}
// order-preserving float<->uint for atomicMax-based segment max
__device__ __forceinline__ unsigned ford(float f) {
    unsigned u = __float_as_uint(f);
    return (u & 0x80000000u) ? ~u : (u | 0x80000000u);
}
__device__ __forceinline__ float iford(unsigned u) {
    return __uint_as_float((u & 0x80000000u) ? (u & 0x7fffffffu) : ~u);
}

// ---- K0: prep weights.
// WTs: W_hh [1536 rows n][512 cols k] -> bf16 in MFMA-B-fragment order:
//   WTs[((T*16 + c)*64 + l)*8 + j] = Whh[n=T*16+(l&15)][k=c*32+(l>>4)*8+j]
//   (T = n-tile 0..95, c = K-chunk 0..15, l = lane, j = elem)
//   One tile T = 16*64*8 = 8192 shorts = 1024 bf16x8 chunks.
// WIT: W_ih [1536][64] -> f32 [64][1536] (for k_gi).
__global__ __launch_bounds__(256) void k_prep(const float* __restrict__ Whh,
                                              const float* __restrict__ Wih,
                                              bf16* __restrict__ WTs,
                                              float* __restrict__ WIT) {
    int t = blockIdx.x * 256 + threadIdx.x;   // 768 blocks -> 196608 exactly
    if (t < 98304) {
        int T = t >> 10, c = (t >> 6) & 15, l = t & 63;
        int n = T * 16 + (l & 15);
        int k = c * 32 + ((l >> 4) << 3);
        const float* src = Whh + (size_t)n * 512 + k;
        bf16x8 v;
#pragma unroll
        for (int j = 0; j < 8; ++j) v[j] = f2bs(src[j]);
        *(bf16x8*)(WTs + (size_t)t * 8) = v;
    } else {
        int u = t - 98304;          // WIT[d][j] = Wih[j][d]
        int d = u / 1536, j = u % 1536;
        WIT[u] = Wih[(size_t)j * 64 + d];
    }
}

// ---- K1: G[n][j] = features[n] . W_ih[j] + b_ih[j]  (per-node gi table, 3 gates)
__global__ __launch_bounds__(256) void k_gi(const float* __restrict__ feat,
                                            const float* __restrict__ WIT,
                                            const float* __restrict__ b_ih,
                                            bf16* __restrict__ G) {
    __shared__ float fs[16][64];
    const int n0 = blockIdx.x * 16;
    const int j = blockIdx.y * 256 + threadIdx.x;
    for (int i = threadIdx.x; i < 16 * 64; i += 256)
        fs[0][i] = feat[(size_t)n0 * 64 + i];
    __syncthreads();
    float acc[16];
    const float b = b_ih[j];
#pragma unroll
    for (int e = 0; e < 16; ++e) acc[e] = b;
    for (int d = 0; d < 64; d += 4) {
        float w0 = WIT[(size_t)(d + 0) * G3 + j];
        float w1 = WIT[(size_t)(d + 1) * G3 + j];
        float w2 = WIT[(size_t)(d + 2) * G3 + j];
        float w3 = WIT[(size_t)(d + 3) * G3 + j];
#pragma unroll
        for (int e = 0; e < 16; ++e) {
            float4 f = *(const float4*)&fs[e][d];
            acc[e] += w0 * f.x + w1 * f.y + w2 * f.z + w3 * f.w;
        }
    }
#pragma unroll
    for (int e = 0; e < 16; ++e)
        G[(size_t)(n0 + e) * G3 + j] = f2b(acc[e]);
}

// ---- K2: GH2[n] = H1[n] @ W_hh^T + b_hh, with H1 recomputed on the fly from G.
// MFMA: 64 nodes/block, 4 waves x 16 rows; A(=H1) frags in VGPR (full K),
// B staged in LDS per gate-triple from pre-swizzled WTs.
__global__ __launch_bounds__(256) void k_gh2(const bf16* __restrict__ G,
                                             const bf16* __restrict__ WTs,
                                             const float* __restrict__ b_hh,
                                             bf16* __restrict__ GH2) {
    __shared__ short Bs[3 * 8192];   // 48 KB
    const int tid = threadIdx.x;
    const int wave = tid >> 6, lane = tid & 63;
    const int m0 = blockIdx.x * 64;
    const int row = m0 + wave * 16 + (lane & 15);
    const int ar = row < N_NODES ? row : N_NODES - 1;
    const int k0 = (lane >> 4) << 3;

    // A frags: H1[ar][k], k = c*32 + k0 + j  (compute GRU step-1 inline)
    bf16x8 afrag[16];
#pragma unroll
    for (int c = 0; c < 16; ++c) {
        const int kb = c * 32 + k0;
        bf16x8 gr = *(const bf16x8*)(G + (size_t)ar * G3 + kb);
        bf16x8 gz = *(const bf16x8*)(G + (size_t)ar * G3 + 512 + kb);
        bf16x8 gn = *(const bf16x8*)(G + (size_t)ar * G3 + 1024 + kb);
        bf16x8 v;
#pragma unroll
        for (int j = 0; j < 8; ++j) {
            float br = b_hh[kb + j], bz = b_hh[512 + kb + j], bn = b_hh[1024 + kb + j];
            float r1 = sigmoidf_(bs2f(gr[j]) + br);
            float z1 = sigmoidf_(bs2f(gz[j]) + bz);
            float n1 = tanhf(bs2f(gn[j]) + r1 * bn);
            v[j] = f2bs((1.0f - z1) * n1);
        }
        afrag[c] = v;
    }

    const int col = lane & 15;
    const int rbase = wave * 16 + ((lane >> 4) << 2);
    for (int jt = 0; jt < 32; ++jt) {
        __syncthreads();
        // stage 3 full tiles: 3 * 1024 bf16x8 chunks = 48 KB
        for (int p = tid; p < 3072; p += 256) {
            int g = p >> 10, q = p & 1023;
            *(bf16x8*)&Bs[g * 8192 + q * 8] =
                *(const bf16x8*)(WTs + ((size_t)(g * 32 + jt) * 8192 + q * 8));
        }
        __syncthreads();
        f32x4 a0 = {0,0,0,0}, a1 = {0,0,0,0}, a2 = {0,0,0,0};
        const int boff = lane * 8;
#pragma unroll
        for (int c = 0; c < 16; ++c) {
            bf16x8 b0 = *(const bf16x8*)&Bs[0 * 8192 + c * 512 + boff];
            bf16x8 b1 = *(const bf16x8*)&Bs[1 * 8192 + c * 512 + boff];
            bf16x8 b2 = *(const bf16x8*)&Bs[2 * 8192 + c * 512 + boff];
            a0 = __builtin_amdgcn_mfma_f32_16x16x32_bf16(afrag[c], b0, a0, 0, 0, 0);
            a1 = __builtin_amdgcn_mfma_f32_16x16x32_bf16(afrag[c], b1, a1, 0, 0, 0);
            a2 = __builtin_amdgcn_mfma_f32_16x16x32_bf16(afrag[c], b2, a2, 0, 0, 0);
        }
        const int cj = jt * 16 + col;
#pragma unroll
        for (int q = 0; q < 4; ++q) {
            int e = m0 + rbase + q;
            if (e < N_NODES) {
                GH2[(size_t)e * G3 + cj] = f2b(a0[q] + b_hh[cj]);
                GH2[(size_t)e * G3 + 512 + cj] = f2b(a1[q] + b_hh[512 + cj]);
                GH2[(size_t)e * G3 + 1024 + cj] = f2b(a2[q] + b_hh[1024 + cj]);
            }
        }
    }
}

// ---- K3: per-edge h2 = GRUstep2(G[i1], GH2[i0], H1[i0]-recomputed)  (elementwise)
// one thread per 8 elements: E*64 threads
__global__ __launch_bounds__(256) void k_h2(const bf16* __restrict__ G,
                                            const bf16* __restrict__ GH2,
                                            const float* __restrict__ b_hh,
                                            const int* __restrict__ emi,
                                            bf16* __restrict__ h2) {
    size_t i = (size_t)blockIdx.x * 256 + threadIdx.x;   // 25000 blocks exactly
    int e = (int)(i >> 6);
    int kc = (int)(i & 63) * 8;
    int i0 = emi[(size_t)e * 3 + 0];
    int i1 = emi[(size_t)e * 3 + 1];
    const bf16* g1 = G + (size_t)i1 * G3;
    const bf16* g0 = G + (size_t)i0 * G3;
    const bf16* gh = GH2 + (size_t)i0 * G3;
    bf16x8 g1r = *(const bf16x8*)(g1 + kc);
    bf16x8 g1z = *(const bf16x8*)(g1 + 512 + kc);
    bf16x8 g1n = *(const bf16x8*)(g1 + 1024 + kc);
    bf16x8 ghr = *(const bf16x8*)(gh + kc);
    bf16x8 ghz = *(const bf16x8*)(gh + 512 + kc);
    bf16x8 ghn = *(const bf16x8*)(gh + 1024 + kc);
    bf16x8 g0r = *(const bf16x8*)(g0 + kc);
    bf16x8 g0z = *(const bf16x8*)(g0 + 512 + kc);
    bf16x8 g0n = *(const bf16x8*)(g0 + 1024 + kc);
    bf16x8 out;
#pragma unroll
    for (int j = 0; j < 8; ++j) {
        float br = b_hh[kc + j], bz = b_hh[512 + kc + j], bn = b_hh[1024 + kc + j];
        // H1[i0] recompute
        float r1 = sigmoidf_(bs2f(g0r[j]) + br);
        float z1 = sigmoidf_(bs2f(g0z[j]) + bz);
        float h1 = (1.0f - z1) * tanhf(bs2f(g0n[j]) + r1 * bn);
        // step 2 (GH2 already includes b_hh)
        float r = sigmoidf_(bs2f(g1r[j]) + bs2f(ghr[j]));
        float z = sigmoidf_(bs2f(g1z[j]) + bs2f(ghz[j]));
        float n = tanhf(bs2f(g1n[j]) + r * bs2f(ghn[j]));
        out[j] = f2bs((1.0f - z) * n + z * h1);
    }
    *(bf16x8*)(h2 + (size_t)e * HID + kc) = out;
}

// ---- K4: gh3 = h2 @ W_hh^T; h3 = GRUstep3(G[i2], gh3+b_hh, h2); h3 overwrites h2.
// MFMA, 64 edges/block; block exclusively owns its 64 rows -> in-place is safe.
__global__ __launch_bounds__(256) void k_gemm3(const bf16* __restrict__ G,
                                               const bf16* __restrict__ WTs,
                                               const float* __restrict__ b_hh,
                                               const int* __restrict__ emi,
                                               bf16* __restrict__ h2) {
    __shared__ short Bs[3 * 8192];   // 48 KB
    __shared__ int si2[64];
    const int tid = threadIdx.x;
    const int wave = tid >> 6, lane = tid & 63;
    const int m0 = blockIdx.x * 64;
    if (tid < 64) {
        int e = m0 + tid;
        si2[tid] = emi[(size_t)(e < N_EDGES ? e : N_EDGES - 1) * 3 + 2];
    }
    const int row = m0 + wave * 16 + (lane & 15);
    const int ar = row < N_EDGES ? row : N_EDGES - 1;
    const int k0 = (lane >> 4) << 3;

    // A frags: h2[ar][c*32 + k0 .. +7], cached full-K in VGPRs
    bf16x8 afrag[16];
#pragma unroll
    for (int c = 0; c < 16; ++c)
        afrag[c] = *(const bf16x8*)(h2 + (size_t)ar * HID + c * 32 + k0);

    const int col = lane & 15;
    const int rbase = wave * 16 + ((lane >> 4) << 2);
    for (int jt = 0; jt < 32; ++jt) {
        __syncthreads();
        // stage 3 full tiles: 3 * 1024 bf16x8 chunks = 48 KB
        for (int p = tid; p < 3072; p += 256) {
            int g = p >> 10, q = p & 1023;
            *(bf16x8*)&Bs[g * 8192 + q * 8] =
                *(const bf16x8*)(WTs + ((size_t)(g * 32 + jt) * 8192 + q * 8));
        }
        __syncthreads();
        f32x4 a0 = {0,0,0,0}, a1 = {0,0,0,0}, a2 = {0,0,0,0};
        const int boff = lane * 8;
#pragma unroll
        for (int c = 0; c < 16; ++c) {
            bf16x8 b0 = *(const bf16x8*)&Bs[0 * 8192 + c * 512 + boff];
            bf16x8 b1 = *(const bf16x8*)&Bs[1 * 8192 + c * 512 + boff];
            bf16x8 b2 = *(const bf16x8*)&Bs[2 * 8192 + c * 512 + boff];
            a0 = __builtin_amdgcn_mfma_f32_16x16x32_bf16(afrag[c], b0, a0, 0, 0, 0);
            a1 = __builtin_amdgcn_mfma_f32_16x16x32_bf16(afrag[c], b1, a1, 0, 0, 0);
            a2 = __builtin_amdgcn_mfma_f32_16x16x32_bf16(afrag[c], b2, a2, 0, 0, 0);
        }
        // epilogue: fuse step-3 gates; write h3 over h2 (cols jt*16+col)
        const int cj = jt * 16 + col;
        const float br = b_hh[cj], bz = b_hh[512 + cj], bn = b_hh[1024 + cj];
#pragma unroll
        for (int q = 0; q < 4; ++q) {
            int e = m0 + rbase + q;
            if (e < N_EDGES) {
                const bf16* g2 = G + (size_t)si2[rbase + q] * G3;
                float r = sigmoidf_(b2f(g2[cj]) + a0[q] + br);
                float z = sigmoidf_(b2f(g2[512 + cj]) + a1[q] + bz);
                float ng = tanhf(b2f(g2[1024 + cj]) + r * (a2[q] + bn));
                float h2v = b2f(h2[(size_t)e * HID + cj]);
                h2[(size_t)e * HID + cj] = f2b((1.0f - z) * ng + z * h2v);
            }
        }
    }
}

// ---- K6: attention logits + leaky relu + segment max (atomic, ordered-uint)
__global__ __launch_bounds__(256) void k_logits(const bf16* __restrict__ eft,
                                                const float* __restrict__ attn,
                                                const int* __restrict__ dst,
                                                float* __restrict__ a,
                                                unsigned* __restrict__ amax) {
    int i = blockIdx.x * 256 + threadIdx.x;  // E*NH exactly
    int e = i >> 3, h = i & 7;
    const __hip_bfloat162* f2 = (const __hip_bfloat162*)(eft + (size_t)e * HID + h * OD);
    const float* at = attn + h * OD;
    float s = 0.f;
#pragma unroll
    for (int d = 0; d < OD / 2; ++d) {
        float2 fv = __bfloat1622float2(f2[d]);
        s += fv.x * at[2 * d] + fv.y * at[2 * d + 1];
    }
    s = (s >= 0.f) ? s : 0.01f * s;
    a[i] = s;
    atomicMax(&amax[(size_t)dst[e] * NH + h], ford(s));
}

// ---- K7: ea = exp(a - amax[dst]); denom += ea
__global__ __launch_bounds__(256) void k_ea(const int* __restrict__ dst,
                                            const unsigned* __restrict__ amax,
                                            float* __restrict__ a,
                                            float* __restrict__ denom) {
    int i = blockIdx.x * 256 + threadIdx.x;
    int e = i >> 3, h = i & 7;
    float m = iford(amax[(size_t)dst[e] * NH + h]);
    float v = __expf(a[i] - m);
    a[i] = v;
    atomicAdd(&denom[(size_t)dst[e] * NH + h], v);
}

// ---- K8: out[dst] += eft * (ea/denom)
__global__ __launch_bounds__(256) void k_agg(const bf16* __restrict__ eft,
                                             const float* __restrict__ a,
                                             const float* __restrict__ denom,
                                             const int* __restrict__ dst,
                                             float* __restrict__ out) {
    size_t i = (size_t)blockIdx.x * 256 + threadIdx.x;  // E*HID exactly
    int e = (int)(i >> 9), k = (int)(i & 511);
    int h = k >> 6;
    int dn = dst[e];
    float alpha = a[e * NH + h] / denom[(size_t)dn * NH + h];
    atomicAdd(&out[(size_t)dn * HID + k], b2f(eft[i]) * alpha);
}

extern "C" void kernel_launch(void* const* d_in, const int* in_sizes, int n_in,
                              void* d_out, int out_size, void* d_ws, size_t ws_size,
                              hipStream_t stream) {
    (void)in_sizes; (void)n_in; (void)ws_size;
    const float* feat = (const float*)d_in[0];
    const float* W_ih = (const float*)d_in[1];
    const float* W_hh = (const float*)d_in[2];
    const float* b_ih = (const float*)d_in[3];
    const float* b_hh = (const float*)d_in[4];
    const float* attn = (const float*)d_in[5];
    const int* emi = (const int*)d_in[6];
    const int* dst = (const int*)d_in[7];
    float* out = (float*)d_out;

    // workspace layout (bytes) — total ~231.7 MB (< proven-safe 253 MB)
    char* ws = (char*)d_ws;
    bf16* G = (bf16*)ws;                               // 61,440,000 B
    bf16* GH2 = (bf16*)(ws + 61440000);                // 61,440,000 B
    bf16* h2 = (bf16*)(ws + 122880000);                // 102,400,000 B (h2 -> h3/eft in-place)
    bf16* WTs = (bf16*)(ws + 225280000);               // 1,572,864 B
    float* WIT = (float*)(ws + 226852864);             // 393,216 B
    float* a = (float*)(ws + 227246080);               // 3,200,000 B
    unsigned* amax = (unsigned*)(ws + 230446080);      // 640,000 B
    float* denom = (float*)(ws + 231086080);           // 640,000 B

    (void)hipMemsetAsync(d_out, 0, (size_t)out_size * sizeof(float), stream);
    (void)hipMemsetAsync(amax, 0, 1280000, stream);    // amax + denom (contiguous)

    k_prep<<<768, 256, 0, stream>>>(W_hh, W_ih, WTs, WIT);
    k_gi<<<dim3(1250, 6), 256, 0, stream>>>(feat, WIT, b_ih, G);
    k_gh2<<<313, 256, 0, stream>>>(G, WTs, b_hh, GH2);
    k_h2<<<25000, 256, 0, stream>>>(G, GH2, b_hh, emi, h2);
    k_gemm3<<<1563, 256, 0, stream>>>(G, WTs, b_hh, emi, h2);
    k_logits<<<3125, 256, 0, stream>>>(h2, attn, dst, a, amax);
    k_ea<<<3125, 256, 0, stream>>>(dst, amax, a, denom);
    k_agg<<<200000, 256, 0, stream>>>(h2, a, denom, dst, out);
}

// Round 6
// 1414.712 us; speedup vs baseline: 2.6217x; 1.1764x over previous
//
#include <hip/hip_runtime.h>
#include <hip/hip_bf16.h>

#define N_NODES 20000
#define N_EDGES 100000
#define HID 512
#define G3 1536   // 3*HID
#define NH 8
#define OD 64

typedef __hip_bfloat16 bf16;
typedef __attribute__((ext_vector_type(8))) short bf16x8;   // 8 bf16 = 4 VGPRs
typedef __attribute__((ext_vector_type(4))) float f32x4;

__device__ __forceinline__ float sigmoidf_(float x) { return 1.0f / (1.0f + __expf(-x)); }
__device__ __forceinline__ float b2f(bf16 b) { return __bfloat162float(b); }
__device__ __forceinline__ bf16 f2b(float f) { return __float2bfloat16(f); }
__device__ __forceinline__ float bs2f(short s) {
    return __uint_as_float(((unsigned)(unsigned short)s) << 16);
}
__device__ __forceinline__ short f2bs(float f) {
    bf16 b = __float2bfloat16(f);
    return *reinterpret_cast<short*>(&b);
}
__device__ __forceinline__ unsigned ford(float f) {
    unsigned u = __float_as_uint(f);
    return (u & 0x80000000u) ? ~u : (u | 0x80000000u);
}
__device__ __forceinline__ float iford(unsigned u) {
    return __uint_as_float((u & 0x80000000u) ? (u & 0x7fffffffu) : ~u);
}

// async global->LDS 16B; falls back to manual copy if builtin missing
__device__ __forceinline__ void g2l16(const void* g, void* l) {
#if __has_builtin(__builtin_amdgcn_global_load_lds)
    __builtin_amdgcn_global_load_lds((const __attribute__((address_space(1))) char*)g,
                                     (__attribute__((address_space(3))) char*)l, 16, 0, 0);
#else
    *(bf16x8*)l = *(const bf16x8*)g;
#endif
}

// G / GH2 layout: gate-interleaved  X[n*1536 + k*3 + g], k in [0,512), g in {r,z,n}

// ---- K0: prep weights (unchanged).
// WTs[((T*16 + c)*64 + l)*8 + j] = Whh[n=T*16+(l&15)][k=c*32+(l>>4)*8+j]
__global__ __launch_bounds__(256) void k_prep(const float* __restrict__ Whh,
                                              const float* __restrict__ Wih,
                                              bf16* __restrict__ WTs,
                                              float* __restrict__ WIT) {
    int t = blockIdx.x * 256 + threadIdx.x;   // 768 blocks -> 196608 exactly
    if (t < 98304) {
        int T = t >> 10, c = (t >> 6) & 15, l = t & 63;
        int n = T * 16 + (l & 15);
        int k = c * 32 + ((l >> 4) << 3);
        const float* src = Whh + (size_t)n * 512 + k;
        bf16x8 v;
#pragma unroll
        for (int j = 0; j < 8; ++j) v[j] = f2bs(src[j]);
        *(bf16x8*)(WTs + (size_t)t * 8) = v;
    } else {
        int u = t - 98304;          // WIT[d][j] = Wih[j][d]
        int d = u / 1536, j = u % 1536;
        WIT[u] = Wih[(size_t)j * 64 + d];
    }
}

// ---- K1: G[n][k][g] = features[n] . W_ih[g*512+k] + b_ih  (interleaved output)
// grid (1250, 2); thread owns k = y*256+tid, all 3 gates
__global__ __launch_bounds__(256) void k_gi(const float* __restrict__ feat,
                                            const float* __restrict__ WIT,
                                            const float* __restrict__ b_ih,
                                            bf16* __restrict__ G) {
    __shared__ float fs[16][64];
    const int n0 = blockIdx.x * 16;
    const int k = blockIdx.y * 256 + threadIdx.x;
    for (int i = threadIdx.x; i < 16 * 64; i += 256)
        fs[0][i] = feat[(size_t)n0 * 64 + i];
    __syncthreads();
    float acc[3][16];
#pragma unroll
    for (int g = 0; g < 3; ++g) {
        float b = b_ih[g * 512 + k];
#pragma unroll
        for (int e = 0; e < 16; ++e) acc[g][e] = b;
    }
    for (int d = 0; d < 64; d += 4) {
        float w[3][4];
#pragma unroll
        for (int u = 0; u < 4; ++u)
#pragma unroll
            for (int g = 0; g < 3; ++g)
                w[g][u] = WIT[(size_t)(d + u) * G3 + g * 512 + k];
#pragma unroll
        for (int e = 0; e < 16; ++e) {
            float4 f = *(const float4*)&fs[e][d];
#pragma unroll
            for (int g = 0; g < 3; ++g)
                acc[g][e] += w[g][0] * f.x + w[g][1] * f.y + w[g][2] * f.z + w[g][3] * f.w;
        }
    }
#pragma unroll
    for (int e = 0; e < 16; ++e) {
        bf16* dst = G + (size_t)(n0 + e) * G3 + k * 3;
#pragma unroll
        for (int g = 0; g < 3; ++g) dst[g] = f2b(acc[g][e]);
    }
}

// ---- K2: GH2[n] = H1[n] @ W_hh^T + b_hh (H1 recomputed inline). M=128/block.
__global__ __launch_bounds__(256) void k_gh2(const bf16* __restrict__ G,
                                             const bf16* __restrict__ WTs,
                                             const float* __restrict__ b_hh,
                                             bf16* __restrict__ GH2) {
    __shared__ short Bs[3 * 8192];   // 48 KB
    const int tid = threadIdx.x;
    const int wave = tid >> 6, lane = tid & 63;
    const int m0 = blockIdx.x * 128;
    const int k0 = (lane >> 4) << 3;

    bf16x8 afrag[2][16];
#pragma unroll
    for (int t = 0; t < 2; ++t) {
        int row = m0 + wave * 32 + t * 16 + (lane & 15);
        int ar = row < N_NODES ? row : N_NODES - 1;
#pragma unroll
        for (int c = 0; c < 16; ++c) {
            const int kb = c * 32 + k0;
            const bf16* gp = G + (size_t)ar * G3 + kb * 3;
            bf16x8 u0 = *(const bf16x8*)gp;
            bf16x8 u1 = *(const bf16x8*)(gp + 8);
            bf16x8 u2 = *(const bf16x8*)(gp + 16);
            short s[24];
#pragma unroll
            for (int j = 0; j < 8; ++j) { s[j] = u0[j]; s[8 + j] = u1[j]; s[16 + j] = u2[j]; }
            bf16x8 v;
#pragma unroll
            for (int j = 0; j < 8; ++j) {
                float br = b_hh[kb + j], bz = b_hh[512 + kb + j], bn = b_hh[1024 + kb + j];
                float r1 = sigmoidf_(bs2f(s[j * 3 + 0]) + br);
                float z1 = sigmoidf_(bs2f(s[j * 3 + 1]) + bz);
                float n1 = tanhf(bs2f(s[j * 3 + 2]) + r1 * bn);
                v[j] = f2bs((1.0f - z1) * n1);
            }
            afrag[t][c] = v;
        }
    }

    const int col = lane & 15;
    const int qb = (lane >> 4) << 2;
    for (int jt = 0; jt < 32; ++jt) {
        __syncthreads();
        for (int p = tid; p < 3072; p += 256) {
            int g = p >> 10, q = p & 1023;
            g2l16(WTs + ((size_t)(g * 32 + jt) * 8192 + q * 8), &Bs[g * 8192 + q * 8]);
        }
        __syncthreads();
        f32x4 acc[2][3];
#pragma unroll
        for (int t = 0; t < 2; ++t)
#pragma unroll
            for (int g = 0; g < 3; ++g) acc[t][g] = (f32x4){0, 0, 0, 0};
        const int boff = lane * 8;
#pragma unroll
        for (int c = 0; c < 16; ++c) {
            bf16x8 b0 = *(const bf16x8*)&Bs[0 * 8192 + c * 512 + boff];
            bf16x8 b1 = *(const bf16x8*)&Bs[1 * 8192 + c * 512 + boff];
            bf16x8 b2 = *(const bf16x8*)&Bs[2 * 8192 + c * 512 + boff];
#pragma unroll
            for (int t = 0; t < 2; ++t) {
                acc[t][0] = __builtin_amdgcn_mfma_f32_16x16x32_bf16(afrag[t][c], b0, acc[t][0], 0, 0, 0);
                acc[t][1] = __builtin_amdgcn_mfma_f32_16x16x32_bf16(afrag[t][c], b1, acc[t][1], 0, 0, 0);
                acc[t][2] = __builtin_amdgcn_mfma_f32_16x16x32_bf16(afrag[t][c], b2, acc[t][2], 0, 0, 0);
            }
        }
        const int cj = jt * 16 + col;
        const float br = b_hh[cj], bz = b_hh[512 + cj], bn = b_hh[1024 + cj];
#pragma unroll
        for (int t = 0; t < 2; ++t)
#pragma unroll
            for (int q = 0; q < 4; ++q) {
                int e = m0 + wave * 32 + t * 16 + qb + q;
                if (e < N_NODES) {
                    bf16* dst = GH2 + (size_t)e * G3 + cj * 3;
                    dst[0] = f2b(acc[t][0][q] + br);
                    dst[1] = f2b(acc[t][1][q] + bz);
                    dst[2] = f2b(acc[t][2][q] + bn);
                }
            }
    }
}

// ---- K3: per-edge h2 = GRUstep2(G[i1], GH2[i0], H1[i0]-recomputed), elementwise
__global__ __launch_bounds__(256) void k_h2(const bf16* __restrict__ G,
                                            const bf16* __restrict__ GH2,
                                            const float* __restrict__ b_hh,
                                            const int* __restrict__ emi,
                                            bf16* __restrict__ h2) {
    size_t i = (size_t)blockIdx.x * 256 + threadIdx.x;   // 25000 blocks exactly
    int e = (int)(i >> 6);
    int kc = (int)(i & 63) * 8;
    int i0 = emi[(size_t)e * 3 + 0];
    int i1 = emi[(size_t)e * 3 + 1];
    const bf16* g1p = G + (size_t)i1 * G3 + kc * 3;
    const bf16* g0p = G + (size_t)i0 * G3 + kc * 3;
    const bf16* ghp = GH2 + (size_t)i0 * G3 + kc * 3;
    short s1[24], s0[24], sh[24];
    {
        bf16x8 a0 = *(const bf16x8*)g1p, a1 = *(const bf16x8*)(g1p + 8), a2 = *(const bf16x8*)(g1p + 16);
        bf16x8 b0 = *(const bf16x8*)g0p, b1 = *(const bf16x8*)(g0p + 8), b2 = *(const bf16x8*)(g0p + 16);
        bf16x8 c0 = *(const bf16x8*)ghp, c1 = *(const bf16x8*)(ghp + 8), c2 = *(const bf16x8*)(ghp + 16);
#pragma unroll
        for (int j = 0; j < 8; ++j) {
            s1[j] = a0[j]; s1[8 + j] = a1[j]; s1[16 + j] = a2[j];
            s0[j] = b0[j]; s0[8 + j] = b1[j]; s0[16 + j] = b2[j];
            sh[j] = c0[j]; sh[8 + j] = c1[j]; sh[16 + j] = c2[j];
        }
    }
    bf16x8 out;
#pragma unroll
    for (int j = 0; j < 8; ++j) {
        float br = b_hh[kc + j], bz = b_hh[512 + kc + j], bn = b_hh[1024 + kc + j];
        float r1 = sigmoidf_(bs2f(s0[j * 3 + 0]) + br);
        float z1 = sigmoidf_(bs2f(s0[j * 3 + 1]) + bz);
        float h1 = (1.0f - z1) * tanhf(bs2f(s0[j * 3 + 2]) + r1 * bn);
        float r = sigmoidf_(bs2f(s1[j * 3 + 0]) + bs2f(sh[j * 3 + 0]));
        float z = sigmoidf_(bs2f(s1[j * 3 + 1]) + bs2f(sh[j * 3 + 1]));
        float n = tanhf(bs2f(s1[j * 3 + 2]) + r * bs2f(sh[j * 3 + 2]));
        out[j] = f2bs((1.0f - z) * n + z * h1);
    }
    *(bf16x8*)(h2 + (size_t)e * HID + kc) = out;
}

// ---- K4: gh3 = h2 @ W_hh^T; h3 = GRUstep3(G[i2], gh3+b_hh, h2) in-place. M=128/block.
__global__ __launch_bounds__(256) void k_gemm3(const bf16* __restrict__ G,
                                               const bf16* __restrict__ WTs,
                                               const float* __restrict__ b_hh,
                                               const int* __restrict__ emi,
                                               bf16* __restrict__ h2) {
    __shared__ short Bs[3 * 8192];   // 48 KB
    __shared__ int si2[128];
    const int tid = threadIdx.x;
    const int wave = tid >> 6, lane = tid & 63;
    const int m0 = blockIdx.x * 128;
    if (tid < 128) {
        int e = m0 + tid;
        si2[tid] = emi[(size_t)(e < N_EDGES ? e : N_EDGES - 1) * 3 + 2];
    }
    const int k0 = (lane >> 4) << 3;

    bf16x8 afrag[2][16];
#pragma unroll
    for (int t = 0; t < 2; ++t) {
        int row = m0 + wave * 32 + t * 16 + (lane & 15);
        int ar = row < N_EDGES ? row : N_EDGES - 1;
#pragma unroll
        for (int c = 0; c < 16; ++c)
            afrag[t][c] = *(const bf16x8*)(h2 + (size_t)ar * HID + c * 32 + k0);
    }

    const int col = lane & 15;
    const int qb = (lane >> 4) << 2;
    for (int jt = 0; jt < 32; ++jt) {
        __syncthreads();
        for (int p = tid; p < 3072; p += 256) {
            int g = p >> 10, q = p & 1023;
            g2l16(WTs + ((size_t)(g * 32 + jt) * 8192 + q * 8), &Bs[g * 8192 + q * 8]);
        }
        __syncthreads();
        f32x4 acc[2][3];
#pragma unroll
        for (int t = 0; t < 2; ++t)
#pragma unroll
            for (int g = 0; g < 3; ++g) acc[t][g] = (f32x4){0, 0, 0, 0};
        const int boff = lane * 8;
#pragma unroll
        for (int c = 0; c < 16; ++c) {
            bf16x8 b0 = *(const bf16x8*)&Bs[0 * 8192 + c * 512 + boff];
            bf16x8 b1 = *(const bf16x8*)&Bs[1 * 8192 + c * 512 + boff];
            bf16x8 b2 = *(const bf16x8*)&Bs[2 * 8192 + c * 512 + boff];
#pragma unroll
            for (int t = 0; t < 2; ++t) {
                acc[t][0] = __builtin_amdgcn_mfma_f32_16x16x32_bf16(afrag[t][c], b0, acc[t][0], 0, 0, 0);
                acc[t][1] = __builtin_amdgcn_mfma_f32_16x16x32_bf16(afrag[t][c], b1, acc[t][1], 0, 0, 0);
                acc[t][2] = __builtin_amdgcn_mfma_f32_16x16x32_bf16(afrag[t][c], b2, acc[t][2], 0, 0, 0);
            }
        }
        const int cj = jt * 16 + col;
        const float br = b_hh[cj], bz = b_hh[512 + cj], bn = b_hh[1024 + cj];
#pragma unroll
        for (int t = 0; t < 2; ++t)
#pragma unroll
            for (int q = 0; q < 4; ++q) {
                int e = m0 + wave * 32 + t * 16 + qb + q;
                if (e < N_EDGES) {
                    const bf16* g2p = G + (size_t)si2[wave * 32 + t * 16 + qb + q] * G3 + cj * 3;
                    float r = sigmoidf_(b2f(g2p[0]) + acc[t][0][q] + br);
                    float z = sigmoidf_(b2f(g2p[1]) + acc[t][1][q] + bz);
                    float ng = tanhf(b2f(g2p[2]) + r * (acc[t][2][q] + bn));
                    float h2v = b2f(h2[(size_t)e * HID + cj]);
                    h2[(size_t)e * HID + cj] = f2b((1.0f - z) * ng + z * h2v);
                }
            }
    }
}

// ---- K6: attention logits + leaky relu + segment max
__global__ __launch_bounds__(256) void k_logits(const bf16* __restrict__ eft,
                                                const float* __restrict__ attn,
                                                const int* __restrict__ dst,
                                                float* __restrict__ a,
                                                unsigned* __restrict__ amax) {
    int i = blockIdx.x * 256 + threadIdx.x;  // E*NH exactly
    int e = i >> 3, h = i & 7;
    const __hip_bfloat162* f2 = (const __hip_bfloat162*)(eft + (size_t)e * HID + h * OD);
    const float* at = attn + h * OD;
    float s = 0.f;
#pragma unroll
    for (int d = 0; d < OD / 2; ++d) {
        float2 fv = __bfloat1622float2(f2[d]);
        s += fv.x * at[2 * d] + fv.y * at[2 * d + 1];
    }
    s = (s >= 0.f) ? s : 0.01f * s;
    a[i] = s;
    atomicMax(&amax[(size_t)dst[e] * NH + h], ford(s));
}

// ---- K7: ea = exp(a - amax[dst]); denom += ea
__global__ __launch_bounds__(256) void k_ea(const int* __restrict__ dst,
                                            const unsigned* __restrict__ amax,
                                            float* __restrict__ a,
                                            float* __restrict__ denom) {
    int i = blockIdx.x * 256 + threadIdx.x;
    int e = i >> 3, h = i & 7;
    float m = iford(amax[(size_t)dst[e] * NH + h]);
    float v = __expf(a[i] - m);
    a[i] = v;
    atomicAdd(&denom[(size_t)dst[e] * NH + h], v);
}

// ---- K8: out[dst] += eft * (ea/denom)
__global__ __launch_bounds__(256) void k_agg(const bf16* __restrict__ eft,
                                             const float* __restrict__ a,
                                             const float* __restrict__ denom,
                                             const int* __restrict__ dst,
                                             float* __restrict__ out) {
    size_t i = (size_t)blockIdx.x * 256 + threadIdx.x;  // E*HID exactly
    int e = (int)(i >> 9), k = (int)(i & 511);
    int h = k >> 6;
    int dn = dst[e];
    float alpha = a[e * NH + h] / denom[(size_t)dn * NH + h];
    atomicAdd(&out[(size_t)dn * HID + k], b2f(eft[i]) * alpha);
}

extern "C" void kernel_launch(void* const* d_in, const int* in_sizes, int n_in,
                              void* d_out, int out_size, void* d_ws, size_t ws_size,
                              hipStream_t stream) {
    (void)in_sizes; (void)n_in; (void)ws_size;
    const float* feat = (const float*)d_in[0];
    const float* W_ih = (const float*)d_in[1];
    const float* W_hh = (const float*)d_in[2];
    const float* b_ih = (const float*)d_in[3];
    const float* b_hh = (const float*)d_in[4];
    const float* attn = (const float*)d_in[5];
    const int* emi = (const int*)d_in[6];
    const int* dst = (const int*)d_in[7];
    float* out = (float*)d_out;

    // workspace layout (bytes) — total ~231.7 MB (< proven-safe 253 MB)
    char* ws = (char*)d_ws;
    bf16* G = (bf16*)ws;                               // 61,440,000 B (interleaved)
    bf16* GH2 = (bf16*)(ws + 61440000);                // 61,440,000 B (interleaved)
    bf16* h2 = (bf16*)(ws + 122880000);                // 102,400,000 B (row-major; h3 in-place)
    bf16* WTs = (bf16*)(ws + 225280000);               // 1,572,864 B
    float* WIT = (float*)(ws + 226852864);             // 393,216 B
    float* a = (float*)(ws + 227246080);               // 3,200,000 B
    unsigned* amax = (unsigned*)(ws + 230446080);      // 640,000 B
    float* denom = (float*)(ws + 231086080);           // 640,000 B

    (void)hipMemsetAsync(d_out, 0, (size_t)out_size * sizeof(float), stream);
    (void)hipMemsetAsync(amax, 0, 1280000, stream);    // amax + denom (contiguous)

    k_prep<<<768, 256, 0, stream>>>(W_hh, W_ih, WTs, WIT);
    k_gi<<<dim3(1250, 2), 256, 0, stream>>>(feat, WIT, b_ih, G);
    k_gh2<<<157, 256, 0, stream>>>(G, WTs, b_hh, GH2);
    k_h2<<<25000, 256, 0, stream>>>(G, GH2, b_hh, emi, h2);
    k_gemm3<<<782, 256, 0, stream>>>(G, WTs, b_hh, emi, h2);
    k_logits<<<3125, 256, 0, stream>>>(h2, attn, dst, a, amax);
    k_ea<<<3125, 256, 0, stream>>>(dst, amax, a, denom);
    k_agg<<<200000, 256, 0, stream>>>(h2, a, denom, dst, out);
}

// Round 7
// 1228.844 us; speedup vs baseline: 3.0182x; 1.1513x over previous
//
#include <hip/hip_runtime.h>
#include <hip/hip_bf16.h>

#define N_NODES 20000
#define N_EDGES 100000
#define HID 512
#define G3 1536   // 3*HID
#define NH 8
#define OD 64

typedef __hip_bfloat16 bf16;
typedef __attribute__((ext_vector_type(8))) short bf16x8;   // 8 bf16 = 4 VGPRs
typedef __attribute__((ext_vector_type(4))) float f32x4;

__device__ __forceinline__ float sigmoidf_(float x) { return 1.0f / (1.0f + __expf(-x)); }
__device__ __forceinline__ float b2f(bf16 b) { return __bfloat162float(b); }
__device__ __forceinline__ bf16 f2b(float f) { return __float2bfloat16(f); }
__device__ __forceinline__ float bs2f(short s) {
    return __uint_as_float(((unsigned)(unsigned short)s) << 16);
}
__device__ __forceinline__ float us2f(unsigned short s) {
    return __uint_as_float(((unsigned)s) << 16);
}
__device__ __forceinline__ short f2bs(float f) {
    bf16 b = __float2bfloat16(f);
    return *reinterpret_cast<short*>(&b);
}
__device__ __forceinline__ unsigned ford(float f) {
    unsigned u = __float_as_uint(f);
    return (u & 0x80000000u) ? ~u : (u | 0x80000000u);
}
__device__ __forceinline__ float iford(unsigned u) {
    return __uint_as_float((u & 0x80000000u) ? (u & 0x7fffffffu) : ~u);
}

// async global->LDS 16B; falls back to manual copy if builtin missing
__device__ __forceinline__ void g2l16(const void* g, void* l) {
#if __has_builtin(__builtin_amdgcn_global_load_lds)
    __builtin_amdgcn_global_load_lds((const __attribute__((address_space(1))) char*)g,
                                     (__attribute__((address_space(3))) char*)l, 16, 0, 0);
#else
    *(bf16x8*)l = *(const bf16x8*)g;
#endif
}

// G / GH2 layout: gate-interleaved  X[n*1536 + k*3 + g], k in [0,512), g in {r,z,n}

// ---- K0: prep weights.
// WTs[((T*16 + c)*64 + l)*8 + j] = Whh[n=T*16+(l&15)][k=c*32+(l>>4)*8+j]
__global__ __launch_bounds__(256) void k_prep(const float* __restrict__ Whh,
                                              const float* __restrict__ Wih,
                                              bf16* __restrict__ WTs,
                                              float* __restrict__ WIT) {
    int t = blockIdx.x * 256 + threadIdx.x;   // 768 blocks -> 196608 exactly
    if (t < 98304) {
        int T = t >> 10, c = (t >> 6) & 15, l = t & 63;
        int n = T * 16 + (l & 15);
        int k = c * 32 + ((l >> 4) << 3);
        const float* src = Whh + (size_t)n * 512 + k;
        bf16x8 v;
#pragma unroll
        for (int j = 0; j < 8; ++j) v[j] = f2bs(src[j]);
        *(bf16x8*)(WTs + (size_t)t * 8) = v;
    } else {
        int u = t - 98304;          // WIT[d][j] = Wih[j][d]
        int d = u / 1536, j = u % 1536;
        WIT[u] = Wih[(size_t)j * 64 + d];
    }
}

// ---- K1: G[n][k][g] = features[n] . W_ih[g*512+k] + b_ih  (interleaved output)
__global__ __launch_bounds__(256) void k_gi(const float* __restrict__ feat,
                                            const float* __restrict__ WIT,
                                            const float* __restrict__ b_ih,
                                            bf16* __restrict__ G) {
    __shared__ float fs[16][64];
    const int n0 = blockIdx.x * 16;
    const int k = blockIdx.y * 256 + threadIdx.x;
    for (int i = threadIdx.x; i < 16 * 64; i += 256)
        fs[0][i] = feat[(size_t)n0 * 64 + i];
    __syncthreads();
    float acc[3][16];
#pragma unroll
    for (int g = 0; g < 3; ++g) {
        float b = b_ih[g * 512 + k];
#pragma unroll
        for (int e = 0; e < 16; ++e) acc[g][e] = b;
    }
    for (int d = 0; d < 64; d += 4) {
        float w[3][4];
#pragma unroll
        for (int u = 0; u < 4; ++u)
#pragma unroll
            for (int g = 0; g < 3; ++g)
                w[g][u] = WIT[(size_t)(d + u) * G3 + g * 512 + k];
#pragma unroll
        for (int e = 0; e < 16; ++e) {
            float4 f = *(const float4*)&fs[e][d];
#pragma unroll
            for (int g = 0; g < 3; ++g)
                acc[g][e] += w[g][0] * f.x + w[g][1] * f.y + w[g][2] * f.z + w[g][3] * f.w;
        }
    }
#pragma unroll
    for (int e = 0; e < 16; ++e) {
        bf16* dst = G + (size_t)(n0 + e) * G3 + k * 3;
#pragma unroll
        for (int g = 0; g < 3; ++g) dst[g] = f2b(acc[g][e]);
    }
}

// ---- K2: GH2[n] = H1[n] @ W_hh^T + b_hh (H1 recomputed inline). M=128/block.
__global__ __launch_bounds__(256) void k_gh2(const bf16* __restrict__ G,
                                             const bf16* __restrict__ WTs,
                                             const float* __restrict__ b_hh,
                                             bf16* __restrict__ GH2) {
    __shared__ short Bs[3 * 8192];   // 48 KB
    const int tid = threadIdx.x;
    const int wave = tid >> 6, lane = tid & 63;
    const int m0 = blockIdx.x * 128;
    const int k0 = (lane >> 4) << 3;

    bf16x8 afrag[2][16];
#pragma unroll
    for (int t = 0; t < 2; ++t) {
        int row = m0 + wave * 32 + t * 16 + (lane & 15);
        int ar = row < N_NODES ? row : N_NODES - 1;
#pragma unroll
        for (int c = 0; c < 16; ++c) {
            const int kb = c * 32 + k0;
            const bf16* gp = G + (size_t)ar * G3 + kb * 3;
            bf16x8 u0 = *(const bf16x8*)gp;
            bf16x8 u1 = *(const bf16x8*)(gp + 8);
            bf16x8 u2 = *(const bf16x8*)(gp + 16);
            short s[24];
#pragma unroll
            for (int j = 0; j < 8; ++j) { s[j] = u0[j]; s[8 + j] = u1[j]; s[16 + j] = u2[j]; }
            bf16x8 v;
#pragma unroll
            for (int j = 0; j < 8; ++j) {
                float br = b_hh[kb + j], bz = b_hh[512 + kb + j], bn = b_hh[1024 + kb + j];
                float r1 = sigmoidf_(bs2f(s[j * 3 + 0]) + br);
                float z1 = sigmoidf_(bs2f(s[j * 3 + 1]) + bz);
                float n1 = tanhf(bs2f(s[j * 3 + 2]) + r1 * bn);
                v[j] = f2bs((1.0f - z1) * n1);
            }
            afrag[t][c] = v;
        }
    }

    const int col = lane & 15;
    const int qb = (lane >> 4) << 2;
    for (int jt = 0; jt < 32; ++jt) {
        __syncthreads();
        for (int p = tid; p < 3072; p += 256) {
            int g = p >> 10, q = p & 1023;
            g2l16(WTs + ((size_t)(g * 32 + jt) * 8192 + q * 8), &Bs[g * 8192 + q * 8]);
        }
        __syncthreads();
        f32x4 acc[2][3];
#pragma unroll
        for (int t = 0; t < 2; ++t)
#pragma unroll
            for (int g = 0; g < 3; ++g) acc[t][g] = (f32x4){0, 0, 0, 0};
        const int boff = lane * 8;
#pragma unroll
        for (int c = 0; c < 16; ++c) {
            bf16x8 b0 = *(const bf16x8*)&Bs[0 * 8192 + c * 512 + boff];
            bf16x8 b1 = *(const bf16x8*)&Bs[1 * 8192 + c * 512 + boff];
            bf16x8 b2 = *(const bf16x8*)&Bs[2 * 8192 + c * 512 + boff];
#pragma unroll
            for (int t = 0; t < 2; ++t) {
                acc[t][0] = __builtin_amdgcn_mfma_f32_16x16x32_bf16(afrag[t][c], b0, acc[t][0], 0, 0, 0);
                acc[t][1] = __builtin_amdgcn_mfma_f32_16x16x32_bf16(afrag[t][c], b1, acc[t][1], 0, 0, 0);
                acc[t][2] = __builtin_amdgcn_mfma_f32_16x16x32_bf16(afrag[t][c], b2, acc[t][2], 0, 0, 0);
            }
        }
        const int cj = jt * 16 + col;
        const float br = b_hh[cj], bz = b_hh[512 + cj], bn = b_hh[1024 + cj];
#pragma unroll
        for (int t = 0; t < 2; ++t)
#pragma unroll
            for (int q = 0; q < 4; ++q) {
                int e = m0 + wave * 32 + t * 16 + qb + q;
                if (e < N_NODES) {
                    bf16* dst = GH2 + (size_t)e * G3 + cj * 3;
                    dst[0] = f2b(acc[t][0][q] + br);
                    dst[1] = f2b(acc[t][1][q] + bz);
                    dst[2] = f2b(acc[t][2][q] + bn);
                }
            }
    }
}

// ---- K3: per-edge h2 = GRUstep2(G[i1], GH2[i0], H1[i0]-recomputed), elementwise
__global__ __launch_bounds__(256) void k_h2(const bf16* __restrict__ G,
                                            const bf16* __restrict__ GH2,
                                            const float* __restrict__ b_hh,
                                            const int* __restrict__ emi,
                                            bf16* __restrict__ h2) {
    size_t i = (size_t)blockIdx.x * 256 + threadIdx.x;   // 25000 blocks exactly
    int e = (int)(i >> 6);
    int kc = (int)(i & 63) * 8;
    int i0 = emi[(size_t)e * 3 + 0];
    int i1 = emi[(size_t)e * 3 + 1];
    const bf16* g1p = G + (size_t)i1 * G3 + kc * 3;
    const bf16* g0p = G + (size_t)i0 * G3 + kc * 3;
    const bf16* ghp = GH2 + (size_t)i0 * G3 + kc * 3;
    short s1[24], s0[24], sh[24];
    {
        bf16x8 a0 = *(const bf16x8*)g1p, a1 = *(const bf16x8*)(g1p + 8), a2 = *(const bf16x8*)(g1p + 16);
        bf16x8 b0 = *(const bf16x8*)g0p, b1 = *(const bf16x8*)(g0p + 8), b2 = *(const bf16x8*)(g0p + 16);
        bf16x8 c0 = *(const bf16x8*)ghp, c1 = *(const bf16x8*)(ghp + 8), c2 = *(const bf16x8*)(ghp + 16);
#pragma unroll
        for (int j = 0; j < 8; ++j) {
            s1[j] = a0[j]; s1[8 + j] = a1[j]; s1[16 + j] = a2[j];
            s0[j] = b0[j]; s0[8 + j] = b1[j]; s0[16 + j] = b2[j];
            sh[j] = c0[j]; sh[8 + j] = c1[j]; sh[16 + j] = c2[j];
        }
    }
    bf16x8 out;
#pragma unroll
    for (int j = 0; j < 8; ++j) {
        float br = b_hh[kc + j], bz = b_hh[512 + kc + j], bn = b_hh[1024 + kc + j];
        float r1 = sigmoidf_(bs2f(s0[j * 3 + 0]) + br);
        float z1 = sigmoidf_(bs2f(s0[j * 3 + 1]) + bz);
        float h1 = (1.0f - z1) * tanhf(bs2f(s0[j * 3 + 2]) + r1 * bn);
        float r = sigmoidf_(bs2f(s1[j * 3 + 0]) + bs2f(sh[j * 3 + 0]));
        float z = sigmoidf_(bs2f(s1[j * 3 + 1]) + bs2f(sh[j * 3 + 1]));
        float n = tanhf(bs2f(s1[j * 3 + 2]) + r * bs2f(sh[j * 3 + 2]));
        out[j] = f2bs((1.0f - z) * n + z * h1);
    }
    *(bf16x8*)(h2 + (size_t)e * HID + kc) = out;
}

// ---- K4: gh3 = h2 @ W_hh^T; h3 = GRUstep3(G[i2], gh3+b_hh, h2) in-place.
// M=64/block (low reg pressure -> 3 blocks/CU); epilogue operands PREFETCHED
// into registers before the MFMA phase so the epilogue is pure compute+store.
__global__ __launch_bounds__(256) void k_gemm3(const bf16* __restrict__ G,
                                               const bf16* __restrict__ WTs,
                                               const float* __restrict__ b_hh,
                                               const int* __restrict__ emi,
                                               bf16* __restrict__ h2) {
    __shared__ short Bs[3 * 8192];   // 48 KB
    __shared__ int si2[64];
    const int tid = threadIdx.x;
    const int wave = tid >> 6, lane = tid & 63;
    const int m0 = blockIdx.x * 64;
    if (tid < 64) {
        int e = m0 + tid;
        si2[tid] = emi[(size_t)(e < N_EDGES ? e : N_EDGES - 1) * 3 + 2];
    }
    const int k0 = (lane >> 4) << 3;

    // A frags: one 16-row m-tile per wave, full K in regs
    bf16x8 afrag[16];
    {
        int row = m0 + wave * 16 + (lane & 15);
        int ar = row < N_EDGES ? row : N_EDGES - 1;
#pragma unroll
        for (int c = 0; c < 16; ++c)
            afrag[c] = *(const bf16x8*)(h2 + (size_t)ar * HID + c * 32 + k0);
    }

    const int col = lane & 15;
    const int qb = (lane >> 4) << 2;
    for (int jt = 0; jt < 32; ++jt) {
        __syncthreads();
        // stage B (async global->LDS)
        for (int p = tid; p < 3072; p += 256) {
            int g = p >> 10, q = p & 1023;
            g2l16(WTs + ((size_t)(g * 32 + jt) * 8192 + q * 8), &Bs[g * 8192 + q * 8]);
        }
        // prefetch epilogue operands (overlaps with staging + MFMA latency)
        const int cj = jt * 16 + col;
        const float br = b_hh[cj], bz = b_hh[512 + cj], bn = b_hh[1024 + cj];
        unsigned short pg[4][3], ph[4];
#pragma unroll
        for (int q = 0; q < 4; ++q) {
            int li = wave * 16 + qb + q;
            int e = m0 + li;
            int ec = e < N_EDGES ? e : N_EDGES - 1;
            const unsigned short* g2p =
                (const unsigned short*)(G + (size_t)si2[li] * G3 + cj * 3);
            pg[q][0] = g2p[0]; pg[q][1] = g2p[1]; pg[q][2] = g2p[2];
            ph[q] = ((const unsigned short*)h2)[(size_t)ec * HID + cj];
        }
        __syncthreads();
        f32x4 a0 = {0, 0, 0, 0}, a1 = {0, 0, 0, 0}, a2 = {0, 0, 0, 0};
        const int boff = lane * 8;
#pragma unroll
        for (int c = 0; c < 16; ++c) {
            bf16x8 b0 = *(const bf16x8*)&Bs[0 * 8192 + c * 512 + boff];
            bf16x8 b1 = *(const bf16x8*)&Bs[1 * 8192 + c * 512 + boff];
            bf16x8 b2 = *(const bf16x8*)&Bs[2 * 8192 + c * 512 + boff];
            a0 = __builtin_amdgcn_mfma_f32_16x16x32_bf16(afrag[c], b0, a0, 0, 0, 0);
            a1 = __builtin_amdgcn_mfma_f32_16x16x32_bf16(afrag[c], b1, a1, 0, 0, 0);
            a2 = __builtin_amdgcn_mfma_f32_16x16x32_bf16(afrag[c], b2, a2, 0, 0, 0);
        }
        // epilogue: pure compute + store (no loads)
#pragma unroll
        for (int q = 0; q < 4; ++q) {
            int e = m0 + wave * 16 + qb + q;
            if (e < N_EDGES) {
                float r = sigmoidf_(us2f(pg[q][0]) + a0[q] + br);
                float z = sigmoidf_(us2f(pg[q][1]) + a1[q] + bz);
                float ng = tanhf(us2f(pg[q][2]) + r * (a2[q] + bn));
                h2[(size_t)e * HID + cj] = f2b((1.0f - z) * ng + z * us2f(ph[q]));
            }
        }
    }
}

// ---- K6: attention logits + leaky relu + segment max
__global__ __launch_bounds__(256) void k_logits(const bf16* __restrict__ eft,
                                                const float* __restrict__ attn,
                                                const int* __restrict__ dst,
                                                float* __restrict__ a,
                                                unsigned* __restrict__ amax) {
    int i = blockIdx.x * 256 + threadIdx.x;  // E*NH exactly
    int e = i >> 3, h = i & 7;
    const __hip_bfloat162* f2 = (const __hip_bfloat162*)(eft + (size_t)e * HID + h * OD);
    const float* at = attn + h * OD;
    float s = 0.f;
#pragma unroll
    for (int d = 0; d < OD / 2; ++d) {
        float2 fv = __bfloat1622float2(f2[d]);
        s += fv.x * at[2 * d] + fv.y * at[2 * d + 1];
    }
    s = (s >= 0.f) ? s : 0.01f * s;
    a[i] = s;
    atomicMax(&amax[(size_t)dst[e] * NH + h], ford(s));
}

// ---- K7: ea = exp(a - amax[dst]); denom += ea
__global__ __launch_bounds__(256) void k_ea(const int* __restrict__ dst,
                                            const unsigned* __restrict__ amax,
                                            float* __restrict__ a,
                                            float* __restrict__ denom) {
    int i = blockIdx.x * 256 + threadIdx.x;
    int e = i >> 3, h = i & 7;
    float m = iford(amax[(size_t)dst[e] * NH + h]);
    float v = __expf(a[i] - m);
    a[i] = v;
    atomicAdd(&denom[(size_t)dst[e] * NH + h], v);
}

// ---- K8: out[dst] += eft * (ea/denom)
__global__ __launch_bounds__(256) void k_agg(const bf16* __restrict__ eft,
                                             const float* __restrict__ a,
                                             const float* __restrict__ denom,
                                             const int* __restrict__ dst,
                                             float* __restrict__ out) {
    size_t i = (size_t)blockIdx.x * 256 + threadIdx.x;  // E*HID exactly
    int e = (int)(i >> 9), k = (int)(i & 511);
    int h = k >> 6;
    int dn = dst[e];
    float alpha = a[e * NH + h] / denom[(size_t)dn * NH + h];
    atomicAdd(&out[(size_t)dn * HID + k], b2f(eft[i]) * alpha);
}

extern "C" void kernel_launch(void* const* d_in, const int* in_sizes, int n_in,
                              void* d_out, int out_size, void* d_ws, size_t ws_size,
                              hipStream_t stream) {
    (void)in_sizes; (void)n_in; (void)ws_size;
    const float* feat = (const float*)d_in[0];
    const float* W_ih = (const float*)d_in[1];
    const float* W_hh = (const float*)d_in[2];
    const float* b_ih = (const float*)d_in[3];
    const float* b_hh = (const float*)d_in[4];
    const float* attn = (const float*)d_in[5];
    const int* emi = (const int*)d_in[6];
    const int* dst = (const int*)d_in[7];
    float* out = (float*)d_out;

    // workspace layout (bytes) — total ~231.7 MB (proven-safe)
    char* ws = (char*)d_ws;
    bf16* G = (bf16*)ws;                               // 61,440,000 B (interleaved)
    bf16* GH2 = (bf16*)(ws + 61440000);                // 61,440,000 B (interleaved)
    bf16* h2 = (bf16*)(ws + 122880000);                // 102,400,000 B (row-major; h3 in-place)
    bf16* WTs = (bf16*)(ws + 225280000);               // 1,572,864 B
    float* WIT = (float*)(ws + 226852864);             // 393,216 B
    float* a = (float*)(ws + 227246080);               // 3,200,000 B
    unsigned* amax = (unsigned*)(ws + 230446080);      // 640,000 B
    float* denom = (float*)(ws + 231086080);           // 640,000 B

    (void)hipMemsetAsync(d_out, 0, (size_t)out_size * sizeof(float), stream);
    (void)hipMemsetAsync(amax, 0, 1280000, stream);    // amax + denom (contiguous)

    k_prep<<<768, 256, 0, stream>>>(W_hh, W_ih, WTs, WIT);
    k_gi<<<dim3(1250, 2), 256, 0, stream>>>(feat, WIT, b_ih, G);
    k_gh2<<<157, 256, 0, stream>>>(G, WTs, b_hh, GH2);
    k_h2<<<25000, 256, 0, stream>>>(G, GH2, b_hh, emi, h2);
    k_gemm3<<<1563, 256, 0, stream>>>(G, WTs, b_hh, emi, h2);
    k_logits<<<3125, 256, 0, stream>>>(h2, attn, dst, a, amax);
    k_ea<<<3125, 256, 0, stream>>>(dst, amax, a, denom);
    k_agg<<<200000, 256, 0, stream>>>(h2, a, denom, dst, out);
}

// Round 8
// 982.731 us; speedup vs baseline: 3.7741x; 1.2504x over previous
//
#include <hip/hip_runtime.h>
#include <hip/hip_bf16.h>

#define N_NODES 20000
#define N_EDGES 100000
#define HID 512
#define G3 1536   // 3*HID
#define NH 8
#define OD 64

typedef __hip_bfloat16 bf16;
typedef __attribute__((ext_vector_type(8))) short bf16x8;   // 8 bf16 = 4 VGPRs
typedef __attribute__((ext_vector_type(4))) float f32x4;

__device__ __forceinline__ float fsig(float x) { return 1.0f / (1.0f + __expf(-x)); }
// saturation-safe fast tanh: x->+inf => 1, x->-inf => -1
__device__ __forceinline__ float ftanh(float x) { return 1.0f - 2.0f / (__expf(2.0f * x) + 1.0f); }
__device__ __forceinline__ float b2f(bf16 b) { return __bfloat162float(b); }
__device__ __forceinline__ bf16 f2b(float f) { return __float2bfloat16(f); }
__device__ __forceinline__ float bs2f(short s) {
    return __uint_as_float(((unsigned)(unsigned short)s) << 16);
}
__device__ __forceinline__ float us2f(unsigned short s) {
    return __uint_as_float(((unsigned)s) << 16);
}
__device__ __forceinline__ short f2bs(float f) {
    bf16 b = __float2bfloat16(f);
    return *reinterpret_cast<short*>(&b);
}
__device__ __forceinline__ unsigned ford(float f) {
    unsigned u = __float_as_uint(f);
    return (u & 0x80000000u) ? ~u : (u | 0x80000000u);
}
__device__ __forceinline__ float iford(unsigned u) {
    return __uint_as_float((u & 0x80000000u) ? (u & 0x7fffffffu) : ~u);
}

// async global->LDS 16B; falls back to manual copy if builtin missing
__device__ __forceinline__ void g2l16(const void* g, void* l) {
#if __has_builtin(__builtin_amdgcn_global_load_lds)
    __builtin_amdgcn_global_load_lds((const __attribute__((address_space(1))) char*)g,
                                     (__attribute__((address_space(3))) char*)l, 16, 0, 0);
#else
    *(bf16x8*)l = *(const bf16x8*)g;
#endif
}

// G / GH2 layout: gate-interleaved  X[n*1536 + k*3 + g], k in [0,512), g in {r,z,n}

// ---- K0: prep weights.
__global__ __launch_bounds__(256) void k_prep(const float* __restrict__ Whh,
                                              const float* __restrict__ Wih,
                                              bf16* __restrict__ WTs,
                                              float* __restrict__ WIT) {
    int t = blockIdx.x * 256 + threadIdx.x;   // 768 blocks -> 196608 exactly
    if (t < 98304) {
        int T = t >> 10, c = (t >> 6) & 15, l = t & 63;
        int n = T * 16 + (l & 15);
        int k = c * 32 + ((l >> 4) << 3);
        const float* src = Whh + (size_t)n * 512 + k;
        bf16x8 v;
#pragma unroll
        for (int j = 0; j < 8; ++j) v[j] = f2bs(src[j]);
        *(bf16x8*)(WTs + (size_t)t * 8) = v;
    } else {
        int u = t - 98304;          // WIT[d][j] = Wih[j][d]
        int d = u / 1536, j = u % 1536;
        WIT[u] = Wih[(size_t)j * 64 + d];
    }
}

// ---- CSR build: count / scan / fill
__global__ __launch_bounds__(256) void k_count(const int* __restrict__ dst,
                                               unsigned* __restrict__ cnt) {
    int e = blockIdx.x * 256 + threadIdx.x;
    if (e < N_EDGES) atomicAdd(&cnt[dst[e]], 1u);
}

#define SCAN_CH 79
__global__ __launch_bounds__(256) void k_scan(const unsigned* __restrict__ cnt,
                                              unsigned* __restrict__ base,
                                              unsigned* __restrict__ cursor) {
    __shared__ unsigned ls[256];
    int t = threadIdx.x;
    int s0 = t * SCAN_CH;
    int s1 = s0 + SCAN_CH < N_NODES ? s0 + SCAN_CH : N_NODES;
    unsigned s = 0;
    for (int i = s0; i < s1; ++i) s += cnt[i];
    ls[t] = s;
    __syncthreads();
    for (int d = 1; d < 256; d <<= 1) {
        unsigned v = (t >= d) ? ls[t - d] : 0u;
        __syncthreads();
        ls[t] += v;
        __syncthreads();
    }
    unsigned run = ls[t] - s;
    for (int i = s0; i < s1; ++i) {
        base[i] = run; cursor[i] = run; run += cnt[i];
    }
    if (t == 255) base[N_NODES] = ls[255];
}

__global__ __launch_bounds__(256) void k_fill(const int* __restrict__ dst,
                                              unsigned* __restrict__ cursor,
                                              unsigned* __restrict__ csr) {
    int e = blockIdx.x * 256 + threadIdx.x;
    if (e < N_EDGES) {
        unsigned p = atomicAdd(&cursor[dst[e]], 1u);
        csr[p] = (unsigned)e;
    }
}

// ---- K1: G[n][k][g] = features[n] . W_ih[g*512+k] + b_ih  (interleaved output)
__global__ __launch_bounds__(256) void k_gi(const float* __restrict__ feat,
                                            const float* __restrict__ WIT,
                                            const float* __restrict__ b_ih,
                                            bf16* __restrict__ G) {
    __shared__ float fs[16][64];
    const int n0 = blockIdx.x * 16;
    const int k = blockIdx.y * 256 + threadIdx.x;
    for (int i = threadIdx.x; i < 16 * 64; i += 256)
        fs[0][i] = feat[(size_t)n0 * 64 + i];
    __syncthreads();
    float acc[3][16];
#pragma unroll
    for (int g = 0; g < 3; ++g) {
        float b = b_ih[g * 512 + k];
#pragma unroll
        for (int e = 0; e < 16; ++e) acc[g][e] = b;
    }
    for (int d = 0; d < 64; d += 4) {
        float w[3][4];
#pragma unroll
        for (int u = 0; u < 4; ++u)
#pragma unroll
            for (int g = 0; g < 3; ++g)
                w[g][u] = WIT[(size_t)(d + u) * G3 + g * 512 + k];
#pragma unroll
        for (int e = 0; e < 16; ++e) {
            float4 f = *(const float4*)&fs[e][d];
#pragma unroll
            for (int g = 0; g < 3; ++g)
                acc[g][e] += w[g][0] * f.x + w[g][1] * f.y + w[g][2] * f.z + w[g][3] * f.w;
        }
    }
#pragma unroll
    for (int e = 0; e < 16; ++e) {
        bf16* dst = G + (size_t)(n0 + e) * G3 + k * 3;
#pragma unroll
        for (int g = 0; g < 3; ++g) dst[g] = f2b(acc[g][e]);
    }
}

// ---- K2: GH2[n] = H1[n] @ W_hh^T + b_hh (H1 recomputed inline). M=128/block.
__global__ __launch_bounds__(256) void k_gh2(const bf16* __restrict__ G,
                                             const bf16* __restrict__ WTs,
                                             const float* __restrict__ b_hh,
                                             bf16* __restrict__ GH2) {
    __shared__ short Bs[3 * 8192];   // 48 KB
    const int tid = threadIdx.x;
    const int wave = tid >> 6, lane = tid & 63;
    const int m0 = blockIdx.x * 128;
    const int k0 = (lane >> 4) << 3;

    bf16x8 afrag[2][16];
#pragma unroll
    for (int t = 0; t < 2; ++t) {
        int row = m0 + wave * 32 + t * 16 + (lane & 15);
        int ar = row < N_NODES ? row : N_NODES - 1;
#pragma unroll
        for (int c = 0; c < 16; ++c) {
            const int kb = c * 32 + k0;
            const bf16* gp = G + (size_t)ar * G3 + kb * 3;
            bf16x8 u0 = *(const bf16x8*)gp;
            bf16x8 u1 = *(const bf16x8*)(gp + 8);
            bf16x8 u2 = *(const bf16x8*)(gp + 16);
            short s[24];
#pragma unroll
            for (int j = 0; j < 8; ++j) { s[j] = u0[j]; s[8 + j] = u1[j]; s[16 + j] = u2[j]; }
            bf16x8 v;
#pragma unroll
            for (int j = 0; j < 8; ++j) {
                float br = b_hh[kb + j], bz = b_hh[512 + kb + j], bn = b_hh[1024 + kb + j];
                float r1 = fsig(bs2f(s[j * 3 + 0]) + br);
                float z1 = fsig(bs2f(s[j * 3 + 1]) + bz);
                float n1 = ftanh(bs2f(s[j * 3 + 2]) + r1 * bn);
                v[j] = f2bs((1.0f - z1) * n1);
            }
            afrag[t][c] = v;
        }
    }

    const int col = lane & 15;
    const int qb = (lane >> 4) << 2;
    for (int jt = 0; jt < 32; ++jt) {
        __syncthreads();
        for (int p = tid; p < 3072; p += 256) {
            int g = p >> 10, q = p & 1023;
            g2l16(WTs + ((size_t)(g * 32 + jt) * 8192 + q * 8), &Bs[g * 8192 + q * 8]);
        }
        __syncthreads();
        f32x4 acc[2][3];
#pragma unroll
        for (int t = 0; t < 2; ++t)
#pragma unroll
            for (int g = 0; g < 3; ++g) acc[t][g] = (f32x4){0, 0, 0, 0};
        const int boff = lane * 8;
#pragma unroll
        for (int c = 0; c < 16; ++c) {
            bf16x8 b0 = *(const bf16x8*)&Bs[0 * 8192 + c * 512 + boff];
            bf16x8 b1 = *(const bf16x8*)&Bs[1 * 8192 + c * 512 + boff];
            bf16x8 b2 = *(const bf16x8*)&Bs[2 * 8192 + c * 512 + boff];
#pragma unroll
            for (int t = 0; t < 2; ++t) {
                acc[t][0] = __builtin_amdgcn_mfma_f32_16x16x32_bf16(afrag[t][c], b0, acc[t][0], 0, 0, 0);
                acc[t][1] = __builtin_amdgcn_mfma_f32_16x16x32_bf16(afrag[t][c], b1, acc[t][1], 0, 0, 0);
                acc[t][2] = __builtin_amdgcn_mfma_f32_16x16x32_bf16(afrag[t][c], b2, acc[t][2], 0, 0, 0);
            }
        }
        const int cj = jt * 16 + col;
        const float br = b_hh[cj], bz = b_hh[512 + cj], bn = b_hh[1024 + cj];
#pragma unroll
        for (int t = 0; t < 2; ++t)
#pragma unroll
            for (int q = 0; q < 4; ++q) {
                int e = m0 + wave * 32 + t * 16 + qb + q;
                if (e < N_NODES) {
                    bf16* dst = GH2 + (size_t)e * G3 + cj * 3;
                    dst[0] = f2b(acc[t][0][q] + br);
                    dst[1] = f2b(acc[t][1][q] + bz);
                    dst[2] = f2b(acc[t][2][q] + bn);
                }
            }
    }
}

// ---- K3: per-edge h2 = GRUstep2(G[i1], GH2[i0], H1[i0]-recomputed), elementwise
__global__ __launch_bounds__(256) void k_h2(const bf16* __restrict__ G,
                                            const bf16* __restrict__ GH2,
                                            const float* __restrict__ b_hh,
                                            const int* __restrict__ emi,
                                            bf16* __restrict__ h2) {
    size_t i = (size_t)blockIdx.x * 256 + threadIdx.x;   // 25000 blocks exactly
    int e = (int)(i >> 6);
    int kc = (int)(i & 63) * 8;
    int i0 = emi[(size_t)e * 3 + 0];
    int i1 = emi[(size_t)e * 3 + 1];
    const bf16* g1p = G + (size_t)i1 * G3 + kc * 3;
    const bf16* g0p = G + (size_t)i0 * G3 + kc * 3;
    const bf16* ghp = GH2 + (size_t)i0 * G3 + kc * 3;
    short s1[24], s0[24], sh[24];
    {
        bf16x8 a0 = *(const bf16x8*)g1p, a1 = *(const bf16x8*)(g1p + 8), a2 = *(const bf16x8*)(g1p + 16);
        bf16x8 b0 = *(const bf16x8*)g0p, b1 = *(const bf16x8*)(g0p + 8), b2 = *(const bf16x8*)(g0p + 16);
        bf16x8 c0 = *(const bf16x8*)ghp, c1 = *(const bf16x8*)(ghp + 8), c2 = *(const bf16x8*)(ghp + 16);
#pragma unroll
        for (int j = 0; j < 8; ++j) {
            s1[j] = a0[j]; s1[8 + j] = a1[j]; s1[16 + j] = a2[j];
            s0[j] = b0[j]; s0[8 + j] = b1[j]; s0[16 + j] = b2[j];
            sh[j] = c0[j]; sh[8 + j] = c1[j]; sh[16 + j] = c2[j];
        }
    }
    bf16x8 out;
#pragma unroll
    for (int j = 0; j < 8; ++j) {
        float br = b_hh[kc + j], bz = b_hh[512 + kc + j], bn = b_hh[1024 + kc + j];
        float r1 = fsig(bs2f(s0[j * 3 + 0]) + br);
        float z1 = fsig(bs2f(s0[j * 3 + 1]) + bz);
        float h1 = (1.0f - z1) * ftanh(bs2f(s0[j * 3 + 2]) + r1 * bn);
        float r = fsig(bs2f(s1[j * 3 + 0]) + bs2f(sh[j * 3 + 0]));
        float z = fsig(bs2f(s1[j * 3 + 1]) + bs2f(sh[j * 3 + 1]));
        float n = ftanh(bs2f(s1[j * 3 + 2]) + r * bs2f(sh[j * 3 + 2]));
        out[j] = f2bs((1.0f - z) * n + z * h1);
    }
    *(bf16x8*)(h2 + (size_t)e * HID + kc) = out;
}

// ---- K4: gh3 = h2 @ W_hh^T; h3 = GRUstep3(G[i2], gh3+b_hh, h2) in-place.
// M=64/block; staging pointers hoisted out of jt loop; epilogue operands prefetched.
__global__ __launch_bounds__(256) void k_gemm3(const bf16* __restrict__ G,
                                               const bf16* __restrict__ WTs,
                                               const float* __restrict__ b_hh,
                                               const int* __restrict__ emi,
                                               bf16* __restrict__ h2) {
    __shared__ short Bs[3 * 8192];   // 48 KB
    __shared__ int si2[64];
    const int tid = threadIdx.x;
    const int wave = tid >> 6, lane = tid & 63;
    const int m0 = blockIdx.x * 64;
    if (tid < 64) {
        int e = m0 + tid;
        si2[tid] = emi[(size_t)(e < N_EDGES ? e : N_EDGES - 1) * 3 + 2];
    }
    const int k0 = (lane >> 4) << 3;

    // A frags: one 16-row m-tile per wave, full K in regs
    bf16x8 afrag[16];
    {
        int row = m0 + wave * 16 + (lane & 15);
        int ar = row < N_EDGES ? row : N_EDGES - 1;
#pragma unroll
        for (int c = 0; c < 16; ++c)
            afrag[c] = *(const bf16x8*)(h2 + (size_t)ar * HID + c * 32 + k0);
    }

    // hoisted staging pointers: p = tid + i*256 -> (g,q) fixed per i
    const bf16* wp[12];
    short* lp[12];
#pragma unroll
    for (int i = 0; i < 12; ++i) {
        int p = tid + i * 256;
        int g = p >> 10, q = p & 1023;
        wp[i] = WTs + (size_t)g * 32 * 8192 + q * 8;
        lp[i] = &Bs[g * 8192 + q * 8];
    }

    const int col = lane & 15;
    const int qb = (lane >> 4) << 2;
    for (int jt = 0; jt < 32; ++jt) {
        __syncthreads();
#pragma unroll
        for (int i = 0; i < 12; ++i) {
            g2l16(wp[i], lp[i]);
            wp[i] += 8192;
        }
        // prefetch epilogue operands (overlaps with staging + MFMA latency)
        const int cj = jt * 16 + col;
        const float br = b_hh[cj], bz = b_hh[512 + cj], bn = b_hh[1024 + cj];
        unsigned short pg[4][3], ph[4];
#pragma unroll
        for (int q = 0; q < 4; ++q) {
            int li = wave * 16 + qb + q;
            int e = m0 + li;
            int ec = e < N_EDGES ? e : N_EDGES - 1;
            const unsigned short* g2p =
                (const unsigned short*)(G + (size_t)si2[li] * G3 + cj * 3);
            pg[q][0] = g2p[0]; pg[q][1] = g2p[1]; pg[q][2] = g2p[2];
            ph[q] = ((const unsigned short*)h2)[(size_t)ec * HID + cj];
        }
        __syncthreads();
        f32x4 a0 = {0, 0, 0, 0}, a1 = {0, 0, 0, 0}, a2 = {0, 0, 0, 0};
        const int boff = lane * 8;
#pragma unroll
        for (int c = 0; c < 16; ++c) {
            bf16x8 b0 = *(const bf16x8*)&Bs[0 * 8192 + c * 512 + boff];
            bf16x8 b1 = *(const bf16x8*)&Bs[1 * 8192 + c * 512 + boff];
            bf16x8 b2 = *(const bf16x8*)&Bs[2 * 8192 + c * 512 + boff];
            a0 = __builtin_amdgcn_mfma_f32_16x16x32_bf16(afrag[c], b0, a0, 0, 0, 0);
            a1 = __builtin_amdgcn_mfma_f32_16x16x32_bf16(afrag[c], b1, a1, 0, 0, 0);
            a2 = __builtin_amdgcn_mfma_f32_16x16x32_bf16(afrag[c], b2, a2, 0, 0, 0);
        }
        // epilogue: pure compute + store (no loads)
#pragma unroll
        for (int q = 0; q < 4; ++q) {
            int e = m0 + wave * 16 + qb + q;
            if (e < N_EDGES) {
                float r = fsig(us2f(pg[q][0]) + a0[q] + br);
                float z = fsig(us2f(pg[q][1]) + a1[q] + bz);
                float ng = ftanh(us2f(pg[q][2]) + r * (a2[q] + bn));
                h2[(size_t)e * HID + cj] = f2b((1.0f - z) * ng + z * us2f(ph[q]));
            }
        }
    }
}

// ---- K6: attention logits + leaky relu + segment max
__global__ __launch_bounds__(256) void k_logits(const bf16* __restrict__ eft,
                                                const float* __restrict__ attn,
                                                const int* __restrict__ dst,
                                                float* __restrict__ a,
                                                unsigned* __restrict__ amax) {
    int i = blockIdx.x * 256 + threadIdx.x;  // E*NH exactly
    int e = i >> 3, h = i & 7;
    const __hip_bfloat162* f2 = (const __hip_bfloat162*)(eft + (size_t)e * HID + h * OD);
    const float* at = attn + h * OD;
    float s = 0.f;
#pragma unroll
    for (int d = 0; d < OD / 2; ++d) {
        float2 fv = __bfloat1622float2(f2[d]);
        s += fv.x * at[2 * d] + fv.y * at[2 * d + 1];
    }
    s = (s >= 0.f) ? s : 0.01f * s;
    a[i] = s;
    atomicMax(&amax[(size_t)dst[e] * NH + h], ford(s));
}

// ---- K7: ea = exp(a - amax[dst]); denom += ea
__global__ __launch_bounds__(256) void k_ea(const int* __restrict__ dst,
                                            const unsigned* __restrict__ amax,
                                            float* __restrict__ a,
                                            float* __restrict__ denom) {
    int i = blockIdx.x * 256 + threadIdx.x;
    int e = i >> 3, h = i & 7;
    float m = iford(amax[(size_t)dst[e] * NH + h]);
    float v = __expf(a[i] - m);
    a[i] = v;
    atomicAdd(&denom[(size_t)dst[e] * NH + h], v);
}

// ---- K8: out[n][k] = sum over incoming edges e: eft[e][k] * ea[e][h] / denom[n][h]
// CSR gather — no atomics; writes every output element exactly once.
__global__ __launch_bounds__(256) void k_out(const bf16* __restrict__ eft,
                                             const float* __restrict__ a,
                                             const float* __restrict__ denom,
                                             const unsigned* __restrict__ base,
                                             const unsigned* __restrict__ csr,
                                             float* __restrict__ out) {
    int n = blockIdx.x;
    int k = blockIdx.y * 256 + threadIdx.x;
    int h = k >> 6;
    unsigned b0 = base[n], b1 = base[n + 1];
    float rden = (b1 > b0) ? 1.0f / denom[(size_t)n * NH + h] : 0.0f;
    float acc = 0.f;
    for (unsigned i = b0; i < b1; ++i) {
        unsigned e = csr[i];
        float al = a[(size_t)e * NH + h];
        acc += b2f(eft[(size_t)e * HID + k]) * al;
    }
    out[(size_t)n * HID + k] = acc * rden;
}

extern "C" void kernel_launch(void* const* d_in, const int* in_sizes, int n_in,
                              void* d_out, int out_size, void* d_ws, size_t ws_size,
                              hipStream_t stream) {
    (void)in_sizes; (void)n_in; (void)ws_size; (void)out_size;
    const float* feat = (const float*)d_in[0];
    const float* W_ih = (const float*)d_in[1];
    const float* W_hh = (const float*)d_in[2];
    const float* b_ih = (const float*)d_in[3];
    const float* b_hh = (const float*)d_in[4];
    const float* attn = (const float*)d_in[5];
    const int* emi = (const int*)d_in[6];
    const int* dst = (const int*)d_in[7];
    float* out = (float*)d_out;

    // workspace layout (bytes) — total ~232.4 MB (proven-safe < 253 MB)
    char* ws = (char*)d_ws;
    bf16* G = (bf16*)ws;                               // 61,440,000 B (interleaved)
    bf16* GH2 = (bf16*)(ws + 61440000);                // 61,440,000 B (interleaved)
    bf16* h2 = (bf16*)(ws + 122880000);                // 102,400,000 B (row-major; h3 in-place)
    bf16* WTs = (bf16*)(ws + 225280000);               // 1,572,864 B
    float* WIT = (float*)(ws + 226852864);             // 393,216 B
    float* a = (float*)(ws + 227246080);               // 3,200,000 B
    unsigned* amax = (unsigned*)(ws + 230446080);      // 640,000 B
    float* denom = (float*)(ws + 231086080);           // 640,000 B
    unsigned* cnt = (unsigned*)(ws + 231726080);       // 80,000 B
    unsigned* base = (unsigned*)(ws + 231806080);      // 80,008 B (20001 u32, pad)
    unsigned* cursor = (unsigned*)(ws + 231886088);    // 80,000 B
    unsigned* csr = (unsigned*)(ws + 231966088);       // 400,000 B -> end 232,366,088

    // zero amax + denom + cnt (contiguous)
    (void)hipMemsetAsync(amax, 0, 1360000, stream);

    k_prep<<<768, 256, 0, stream>>>(W_hh, W_ih, WTs, WIT);
    k_count<<<391, 256, 0, stream>>>(dst, cnt);
    k_scan<<<1, 256, 0, stream>>>(cnt, base, cursor);
    k_fill<<<391, 256, 0, stream>>>(dst, cursor, csr);
    k_gi<<<dim3(1250, 2), 256, 0, stream>>>(feat, WIT, b_ih, G);
    k_gh2<<<157, 256, 0, stream>>>(G, WTs, b_hh, GH2);
    k_h2<<<25000, 256, 0, stream>>>(G, GH2, b_hh, emi, h2);
    k_gemm3<<<1563, 256, 0, stream>>>(G, WTs, b_hh, emi, h2);
    k_logits<<<3125, 256, 0, stream>>>(h2, attn, dst, a, amax);
    k_ea<<<3125, 256, 0, stream>>>(dst, amax, a, denom);
    k_out<<<dim3(N_NODES, 2), 256, 0, stream>>>(h2, a, denom, base, csr, out);
}

// Round 9
// 863.000 us; speedup vs baseline: 4.2977x; 1.1387x over previous
//
#include <hip/hip_runtime.h>
#include <hip/hip_bf16.h>

#define N_NODES 20000
#define N_EDGES 100000
#define HID 512
#define G3 1536   // 3*HID
#define NH 8
#define OD 64

typedef __hip_bfloat16 bf16;
typedef __attribute__((ext_vector_type(8))) short bf16x8;   // 8 bf16 = 4 VGPRs
typedef __attribute__((ext_vector_type(4))) float f32x4;

__device__ __forceinline__ float fsig(float x) { return 1.0f / (1.0f + __expf(-x)); }
// saturation-safe fast tanh
__device__ __forceinline__ float ftanh(float x) { return 1.0f - 2.0f / (__expf(2.0f * x) + 1.0f); }
__device__ __forceinline__ float b2f(bf16 b) { return __bfloat162float(b); }
__device__ __forceinline__ bf16 f2b(float f) { return __float2bfloat16(f); }
__device__ __forceinline__ float bs2f(short s) {
    return __uint_as_float(((unsigned)(unsigned short)s) << 16);
}
__device__ __forceinline__ float us2f(unsigned short s) {
    return __uint_as_float(((unsigned)s) << 16);
}
__device__ __forceinline__ short f2bs(float f) {
    bf16 b = __float2bfloat16(f);
    return *reinterpret_cast<short*>(&b);
}
__device__ __forceinline__ unsigned ford(float f) {
    unsigned u = __float_as_uint(f);
    return (u & 0x80000000u) ? ~u : (u | 0x80000000u);
}
__device__ __forceinline__ float iford(unsigned u) {
    return __uint_as_float((u & 0x80000000u) ? (u & 0x7fffffffu) : ~u);
}

// async global->LDS 16B; falls back to manual copy if builtin missing
__device__ __forceinline__ void g2l16(const void* g, void* l) {
#if __has_builtin(__builtin_amdgcn_global_load_lds)
    __builtin_amdgcn_global_load_lds((const __attribute__((address_space(1))) char*)g,
                                     (__attribute__((address_space(3))) char*)l, 16, 0, 0);
#else
    *(bf16x8*)l = *(const bf16x8*)g;
#endif
}

// G / GH2 layout: gate-interleaved  X[n*1536 + k*3 + g]; H1/h2: row-major [n][512]

// ---- K0: prep weights.
__global__ __launch_bounds__(256) void k_prep(const float* __restrict__ Whh,
                                              const float* __restrict__ Wih,
                                              bf16* __restrict__ WTs,
                                              float* __restrict__ WIT) {
    int t = blockIdx.x * 256 + threadIdx.x;   // 768 blocks -> 196608 exactly
    if (t < 98304) {
        int T = t >> 10, c = (t >> 6) & 15, l = t & 63;
        int n = T * 16 + (l & 15);
        int k = c * 32 + ((l >> 4) << 3);
        const float* src = Whh + (size_t)n * 512 + k;
        bf16x8 v;
#pragma unroll
        for (int j = 0; j < 8; ++j) v[j] = f2bs(src[j]);
        *(bf16x8*)(WTs + (size_t)t * 8) = v;
    } else {
        int u = t - 98304;          // WIT[d][j] = Wih[j][d]
        int d = u / 1536, j = u % 1536;
        WIT[u] = Wih[(size_t)j * 64 + d];
    }
}

// ---- CSR build: count / scan / fill
__global__ __launch_bounds__(256) void k_count(const int* __restrict__ dst,
                                               unsigned* __restrict__ cnt) {
    int e = blockIdx.x * 256 + threadIdx.x;
    if (e < N_EDGES) atomicAdd(&cnt[dst[e]], 1u);
}

#define SCAN_CH 79
__global__ __launch_bounds__(256) void k_scan(const unsigned* __restrict__ cnt,
                                              unsigned* __restrict__ base,
                                              unsigned* __restrict__ cursor) {
    __shared__ unsigned ls[256];
    int t = threadIdx.x;
    int s0 = t * SCAN_CH;
    int s1 = s0 + SCAN_CH < N_NODES ? s0 + SCAN_CH : N_NODES;
    unsigned s = 0;
    for (int i = s0; i < s1; ++i) s += cnt[i];
    ls[t] = s;
    __syncthreads();
    for (int d = 1; d < 256; d <<= 1) {
        unsigned v = (t >= d) ? ls[t - d] : 0u;
        __syncthreads();
        ls[t] += v;
        __syncthreads();
    }
    unsigned run = ls[t] - s;
    for (int i = s0; i < s1; ++i) {
        base[i] = run; cursor[i] = run; run += cnt[i];
    }
    if (t == 255) base[N_NODES] = ls[255];
}

__global__ __launch_bounds__(256) void k_fill(const int* __restrict__ dst,
                                              unsigned* __restrict__ cursor,
                                              unsigned* __restrict__ csr) {
    int e = blockIdx.x * 256 + threadIdx.x;
    if (e < N_EDGES) {
        unsigned p = atomicAdd(&cursor[dst[e]], 1u);
        csr[p] = (unsigned)e;
    }
}

// ---- K1: G[n][k][g] = features[n].W_ih + b_ih (interleaved); also H1[n][k] (free)
__global__ __launch_bounds__(256) void k_gi(const float* __restrict__ feat,
                                            const float* __restrict__ WIT,
                                            const float* __restrict__ b_ih,
                                            const float* __restrict__ b_hh,
                                            bf16* __restrict__ G,
                                            bf16* __restrict__ H1) {
    __shared__ float fs[16][64];
    const int n0 = blockIdx.x * 16;
    const int k = blockIdx.y * 256 + threadIdx.x;
    for (int i = threadIdx.x; i < 16 * 64; i += 256)
        fs[0][i] = feat[(size_t)n0 * 64 + i];
    __syncthreads();
    float acc[3][16];
#pragma unroll
    for (int g = 0; g < 3; ++g) {
        float b = b_ih[g * 512 + k];
#pragma unroll
        for (int e = 0; e < 16; ++e) acc[g][e] = b;
    }
    for (int d = 0; d < 64; d += 4) {
        float w[3][4];
#pragma unroll
        for (int u = 0; u < 4; ++u)
#pragma unroll
            for (int g = 0; g < 3; ++g)
                w[g][u] = WIT[(size_t)(d + u) * G3 + g * 512 + k];
#pragma unroll
        for (int e = 0; e < 16; ++e) {
            float4 f = *(const float4*)&fs[e][d];
#pragma unroll
            for (int g = 0; g < 3; ++g)
                acc[g][e] += w[g][0] * f.x + w[g][1] * f.y + w[g][2] * f.z + w[g][3] * f.w;
        }
    }
    const float br = b_hh[k], bz = b_hh[512 + k], bn = b_hh[1024 + k];
#pragma unroll
    for (int e = 0; e < 16; ++e) {
        bf16* dst = G + (size_t)(n0 + e) * G3 + k * 3;
        dst[0] = f2b(acc[0][e]);
        dst[1] = f2b(acc[1][e]);
        dst[2] = f2b(acc[2][e]);
        float r1 = fsig(acc[0][e] + br);
        float z1 = fsig(acc[1][e] + bz);
        float n1 = ftanh(acc[2][e] + r1 * bn);
        H1[(size_t)(n0 + e) * HID + k] = f2b((1.0f - z1) * n1);
    }
}

// ---- K2: GH2[n] = H1[n] @ W_hh^T + b_hh. M=128/block, A from H1 (contiguous).
__global__ __launch_bounds__(256, 2) void k_gh2(const bf16* __restrict__ H1,
                                                const bf16* __restrict__ WTs,
                                                const float* __restrict__ b_hh,
                                                bf16* __restrict__ GH2) {
    __shared__ short Bs[3 * 8192];   // 48 KB
    const int tid = threadIdx.x;
    const int wave = tid >> 6, lane = tid & 63;
    const int m0 = blockIdx.x * 128;
    const int k0 = (lane >> 4) << 3;

    bf16x8 afrag[2][16];
#pragma unroll
    for (int t = 0; t < 2; ++t) {
        int row = m0 + wave * 32 + t * 16 + (lane & 15);
        int ar = row < N_NODES ? row : N_NODES - 1;
#pragma unroll
        for (int c = 0; c < 16; ++c)
            afrag[t][c] = *(const bf16x8*)(H1 + (size_t)ar * HID + c * 32 + k0);
    }

    const bf16* wp[12];
    short* lp[12];
#pragma unroll
    for (int i = 0; i < 12; ++i) {
        int p = tid + i * 256;
        int g = p >> 10, q = p & 1023;
        wp[i] = WTs + (size_t)g * 32 * 8192 + q * 8;
        lp[i] = &Bs[g * 8192 + q * 8];
    }

    const int col = lane & 15;
    const int qb = (lane >> 4) << 2;
    for (int jt = 0; jt < 32; ++jt) {
        __syncthreads();
#pragma unroll
        for (int i = 0; i < 12; ++i) {
            g2l16(wp[i], lp[i]);
            wp[i] += 8192;
        }
        __syncthreads();
        f32x4 acc[2][3];
#pragma unroll
        for (int t = 0; t < 2; ++t)
#pragma unroll
            for (int g = 0; g < 3; ++g) acc[t][g] = (f32x4){0, 0, 0, 0};
        const int boff = lane * 8;
#pragma unroll
        for (int c = 0; c < 16; ++c) {
            bf16x8 b0 = *(const bf16x8*)&Bs[0 * 8192 + c * 512 + boff];
            bf16x8 b1 = *(const bf16x8*)&Bs[1 * 8192 + c * 512 + boff];
            bf16x8 b2 = *(const bf16x8*)&Bs[2 * 8192 + c * 512 + boff];
#pragma unroll
            for (int t = 0; t < 2; ++t) {
                acc[t][0] = __builtin_amdgcn_mfma_f32_16x16x32_bf16(afrag[t][c], b0, acc[t][0], 0, 0, 0);
                acc[t][1] = __builtin_amdgcn_mfma_f32_16x16x32_bf16(afrag[t][c], b1, acc[t][1], 0, 0, 0);
                acc[t][2] = __builtin_amdgcn_mfma_f32_16x16x32_bf16(afrag[t][c], b2, acc[t][2], 0, 0, 0);
            }
        }
        const int cj = jt * 16 + col;
        const float br = b_hh[cj], bz = b_hh[512 + cj], bn = b_hh[1024 + cj];
#pragma unroll
        for (int t = 0; t < 2; ++t)
#pragma unroll
            for (int q = 0; q < 4; ++q) {
                int e = m0 + wave * 32 + t * 16 + qb + q;
                if (e < N_NODES) {
                    bf16* dst = GH2 + (size_t)e * G3 + cj * 3;
                    dst[0] = f2b(acc[t][0][q] + br);
                    dst[1] = f2b(acc[t][1][q] + bz);
                    dst[2] = f2b(acc[t][2][q] + bn);
                }
            }
    }
}

// ---- K3: per-edge h2 = GRUstep2(G[i1], GH2[i0], H1[i0]) elementwise
__global__ __launch_bounds__(256) void k_h2(const bf16* __restrict__ G,
                                            const bf16* __restrict__ GH2,
                                            const bf16* __restrict__ H1,
                                            const int* __restrict__ emi,
                                            bf16* __restrict__ h2) {
    size_t i = (size_t)blockIdx.x * 256 + threadIdx.x;   // 25000 blocks exactly
    int e = (int)(i >> 6);
    int kc = (int)(i & 63) * 8;
    int i0 = emi[(size_t)e * 3 + 0];
    int i1 = emi[(size_t)e * 3 + 1];
    const bf16* g1p = G + (size_t)i1 * G3 + kc * 3;
    const bf16* ghp = GH2 + (size_t)i0 * G3 + kc * 3;
    bf16x8 h1v = *(const bf16x8*)(H1 + (size_t)i0 * HID + kc);
    short s1[24], sh[24];
    {
        bf16x8 a0 = *(const bf16x8*)g1p, a1 = *(const bf16x8*)(g1p + 8), a2 = *(const bf16x8*)(g1p + 16);
        bf16x8 c0 = *(const bf16x8*)ghp, c1 = *(const bf16x8*)(ghp + 8), c2 = *(const bf16x8*)(ghp + 16);
#pragma unroll
        for (int j = 0; j < 8; ++j) {
            s1[j] = a0[j]; s1[8 + j] = a1[j]; s1[16 + j] = a2[j];
            sh[j] = c0[j]; sh[8 + j] = c1[j]; sh[16 + j] = c2[j];
        }
    }
    bf16x8 out;
#pragma unroll
    for (int j = 0; j < 8; ++j) {
        float r = fsig(bs2f(s1[j * 3 + 0]) + bs2f(sh[j * 3 + 0]));
        float z = fsig(bs2f(s1[j * 3 + 1]) + bs2f(sh[j * 3 + 1]));
        float n = ftanh(bs2f(s1[j * 3 + 2]) + r * bs2f(sh[j * 3 + 2]));
        out[j] = f2bs((1.0f - z) * n + z * bs2f(h1v[j]));
    }
    *(bf16x8*)(h2 + (size_t)e * HID + kc) = out;
}

// ---- K4: gh3 = h2 @ W_hh^T; h3 = GRUstep3(G[i2], gh3+b_hh, h2) in-place.
// M=128/block, 2 row-tiles per wave share each B-frag read (halves LDS traffic).
__global__ __launch_bounds__(256, 2) void k_gemm3(const bf16* __restrict__ G,
                                                  const bf16* __restrict__ WTs,
                                                  const float* __restrict__ b_hh,
                                                  const int* __restrict__ emi,
                                                  bf16* __restrict__ h2) {
    __shared__ short Bs[3 * 8192];   // 48 KB
    __shared__ int si2[128];
    const int tid = threadIdx.x;
    const int wave = tid >> 6, lane = tid & 63;
    const int m0 = blockIdx.x * 128;
    if (tid < 128) {
        int e = m0 + tid;
        si2[tid] = emi[(size_t)(e < N_EDGES ? e : N_EDGES - 1) * 3 + 2];
    }
    const int k0 = (lane >> 4) << 3;

    bf16x8 afrag[2][16];
#pragma unroll
    for (int t = 0; t < 2; ++t) {
        int row = m0 + wave * 32 + t * 16 + (lane & 15);
        int ar = row < N_EDGES ? row : N_EDGES - 1;
#pragma unroll
        for (int c = 0; c < 16; ++c)
            afrag[t][c] = *(const bf16x8*)(h2 + (size_t)ar * HID + c * 32 + k0);
    }

    const bf16* wp[12];
    short* lp[12];
#pragma unroll
    for (int i = 0; i < 12; ++i) {
        int p = tid + i * 256;
        int g = p >> 10, q = p & 1023;
        wp[i] = WTs + (size_t)g * 32 * 8192 + q * 8;
        lp[i] = &Bs[g * 8192 + q * 8];
    }

    const int col = lane & 15;
    const int qb = (lane >> 4) << 2;
    for (int jt = 0; jt < 32; ++jt) {
        __syncthreads();
#pragma unroll
        for (int i = 0; i < 12; ++i) {
            g2l16(wp[i], lp[i]);
            wp[i] += 8192;
        }
        // prefetch epilogue operands (overlaps with staging + MFMA)
        const int cj = jt * 16 + col;
        const float br = b_hh[cj], bz = b_hh[512 + cj], bn = b_hh[1024 + cj];
        unsigned short pg[2][4][3], ph[2][4];
#pragma unroll
        for (int t = 0; t < 2; ++t)
#pragma unroll
            for (int q = 0; q < 4; ++q) {
                int li = wave * 32 + t * 16 + qb + q;
                int e = m0 + li;
                int ec = e < N_EDGES ? e : N_EDGES - 1;
                const unsigned short* g2p =
                    (const unsigned short*)(G + (size_t)si2[li] * G3 + cj * 3);
                pg[t][q][0] = g2p[0]; pg[t][q][1] = g2p[1]; pg[t][q][2] = g2p[2];
                ph[t][q] = ((const unsigned short*)h2)[(size_t)ec * HID + cj];
            }
        __syncthreads();
        f32x4 acc[2][3];
#pragma unroll
        for (int t = 0; t < 2; ++t)
#pragma unroll
            for (int g = 0; g < 3; ++g) acc[t][g] = (f32x4){0, 0, 0, 0};
        const int boff = lane * 8;
#pragma unroll
        for (int c = 0; c < 16; ++c) {
            bf16x8 b0 = *(const bf16x8*)&Bs[0 * 8192 + c * 512 + boff];
            bf16x8 b1 = *(const bf16x8*)&Bs[1 * 8192 + c * 512 + boff];
            bf16x8 b2 = *(const bf16x8*)&Bs[2 * 8192 + c * 512 + boff];
#pragma unroll
            for (int t = 0; t < 2; ++t) {
                acc[t][0] = __builtin_amdgcn_mfma_f32_16x16x32_bf16(afrag[t][c], b0, acc[t][0], 0, 0, 0);
                acc[t][1] = __builtin_amdgcn_mfma_f32_16x16x32_bf16(afrag[t][c], b1, acc[t][1], 0, 0, 0);
                acc[t][2] = __builtin_amdgcn_mfma_f32_16x16x32_bf16(afrag[t][c], b2, acc[t][2], 0, 0, 0);
            }
        }
        // epilogue: pure compute + store
#pragma unroll
        for (int t = 0; t < 2; ++t)
#pragma unroll
            for (int q = 0; q < 4; ++q) {
                int e = m0 + wave * 32 + t * 16 + qb + q;
                if (e < N_EDGES) {
                    float r = fsig(us2f(pg[t][q][0]) + acc[t][0][q] + br);
                    float z = fsig(us2f(pg[t][q][1]) + acc[t][1][q] + bz);
                    float ng = ftanh(us2f(pg[t][q][2]) + r * (acc[t][2][q] + bn));
                    h2[(size_t)e * HID + cj] = f2b((1.0f - z) * ng + z * us2f(ph[t][q]));
                }
            }
    }
}

// ---- K6: attention logits + leaky relu + segment max
__global__ __launch_bounds__(256) void k_logits(const bf16* __restrict__ eft,
                                                const float* __restrict__ attn,
                                                const int* __restrict__ dst,
                                                float* __restrict__ a,
                                                unsigned* __restrict__ amax) {
    int i = blockIdx.x * 256 + threadIdx.x;  // E*NH exactly
    int e = i >> 3, h = i & 7;
    const __hip_bfloat162* f2 = (const __hip_bfloat162*)(eft + (size_t)e * HID + h * OD);
    const float* at = attn + h * OD;
    float s = 0.f;
#pragma unroll
    for (int d = 0; d < OD / 2; ++d) {
        float2 fv = __bfloat1622float2(f2[d]);
        s += fv.x * at[2 * d] + fv.y * at[2 * d + 1];
    }
    s = (s >= 0.f) ? s : 0.01f * s;
    a[i] = s;
    atomicMax(&amax[(size_t)dst[e] * NH + h], ford(s));
}

// ---- K7: ea = exp(a - amax[dst]); denom += ea
__global__ __launch_bounds__(256) void k_ea(const int* __restrict__ dst,
                                            const unsigned* __restrict__ amax,
                                            float* __restrict__ a,
                                            float* __restrict__ denom) {
    int i = blockIdx.x * 256 + threadIdx.x;
    int e = i >> 3, h = i & 7;
    float m = iford(amax[(size_t)dst[e] * NH + h]);
    float v = __expf(a[i] - m);
    a[i] = v;
    atomicAdd(&denom[(size_t)dst[e] * NH + h], v);
}

// ---- K8: out[n][k] = sum_e eft[e][k]*ea[e][h] / denom[n][h]   (CSR, no atomics)
__global__ __launch_bounds__(256) void k_out(const bf16* __restrict__ eft,
                                             const float* __restrict__ a,
                                             const float* __restrict__ denom,
                                             const unsigned* __restrict__ base,
                                             const unsigned* __restrict__ csr,
                                             float* __restrict__ out) {
    int n = blockIdx.x;
    int k = blockIdx.y * 256 + threadIdx.x;
    int h = k >> 6;
    unsigned b0 = base[n], b1 = base[n + 1];
    float rden = (b1 > b0) ? 1.0f / denom[(size_t)n * NH + h] : 0.0f;
    float acc = 0.f;
    for (unsigned i = b0; i < b1; ++i) {
        unsigned e = csr[i];
        float al = a[(size_t)e * NH + h];
        acc += b2f(eft[(size_t)e * HID + k]) * al;
    }
    out[(size_t)n * HID + k] = acc * rden;
}

extern "C" void kernel_launch(void* const* d_in, const int* in_sizes, int n_in,
                              void* d_out, int out_size, void* d_ws, size_t ws_size,
                              hipStream_t stream) {
    (void)in_sizes; (void)n_in; (void)ws_size; (void)out_size;
    const float* feat = (const float*)d_in[0];
    const float* W_ih = (const float*)d_in[1];
    const float* W_hh = (const float*)d_in[2];
    const float* b_ih = (const float*)d_in[3];
    const float* b_hh = (const float*)d_in[4];
    const float* attn = (const float*)d_in[5];
    const int* emi = (const int*)d_in[6];
    const int* dst = (const int*)d_in[7];
    float* out = (float*)d_out;

    // workspace layout (bytes) — total ~252.8 MB (<= proven-safe ~253.7 MB)
    char* ws = (char*)d_ws;
    bf16* G = (bf16*)ws;                               // 61,440,000 B (interleaved)
    bf16* GH2 = (bf16*)(ws + 61440000);                // 61,440,000 B (interleaved)
    bf16* h2 = (bf16*)(ws + 122880000);                // 102,400,000 B (row-major; h3 in-place)
    bf16* WTs = (bf16*)(ws + 225280000);               // 1,572,864 B
    float* WIT = (float*)(ws + 226852864);             // 393,216 B
    float* a = (float*)(ws + 227246080);               // 3,200,000 B
    unsigned* amax = (unsigned*)(ws + 230446080);      // 640,000 B
    float* denom = (float*)(ws + 231086080);           // 640,000 B
    unsigned* cnt = (unsigned*)(ws + 231726080);       // 80,000 B
    unsigned* base = (unsigned*)(ws + 231806080);      // 80,008 B (20001 u32, pad)
    unsigned* cursor = (unsigned*)(ws + 231886088);    // 80,000 B
    unsigned* csr = (unsigned*)(ws + 231966088);       // 400,000 B
    bf16* H1 = (bf16*)(ws + 232366088);                // 20,480,000 B -> end 252,846,088

    // zero amax + denom + cnt (contiguous)
    (void)hipMemsetAsync(amax, 0, 1360000, stream);

    k_prep<<<768, 256, 0, stream>>>(W_hh, W_ih, WTs, WIT);
    k_count<<<391, 256, 0, stream>>>(dst, cnt);
    k_scan<<<1, 256, 0, stream>>>(cnt, base, cursor);
    k_fill<<<391, 256, 0, stream>>>(dst, cursor, csr);
    k_gi<<<dim3(1250, 2), 256, 0, stream>>>(feat, WIT, b_ih, b_hh, G, H1);
    k_gh2<<<157, 256, 0, stream>>>(H1, WTs, b_hh, GH2);
    k_h2<<<25000, 256, 0, stream>>>(G, GH2, H1, emi, h2);
    k_gemm3<<<782, 256, 0, stream>>>(G, WTs, b_hh, emi, h2);
    k_logits<<<3125, 256, 0, stream>>>(h2, attn, dst, a, amax);
    k_ea<<<3125, 256, 0, stream>>>(dst, amax, a, denom);
    k_out<<<dim3(N_NODES, 2), 256, 0, stream>>>(h2, a, denom, base, csr, out);
}

// Round 10
// 804.756 us; speedup vs baseline: 4.6088x; 1.0724x over previous
//
#include <hip/hip_runtime.h>
#include <hip/hip_bf16.h>

#define N_NODES 20000
#define N_EDGES 100000
#define HID 512
#define G3 1536   // 3*HID
#define NH 8
#define OD 64

typedef __hip_bfloat16 bf16;
typedef __attribute__((ext_vector_type(8))) short bf16x8;   // 8 bf16 = 4 VGPRs
typedef __attribute__((ext_vector_type(4))) float f32x4;

__device__ __forceinline__ float frcp(float x) { return __builtin_amdgcn_rcpf(x); }
__device__ __forceinline__ float fsig(float x) { return frcp(1.0f + __expf(-x)); }
// saturation-safe fast tanh (rcp-based)
__device__ __forceinline__ float ftanh(float x) { return 1.0f - 2.0f * frcp(__expf(2.0f * x) + 1.0f); }
__device__ __forceinline__ float b2f(bf16 b) { return __bfloat162float(b); }
__device__ __forceinline__ bf16 f2b(float f) { return __float2bfloat16(f); }
__device__ __forceinline__ float bs2f(short s) {
    return __uint_as_float(((unsigned)(unsigned short)s) << 16);
}
__device__ __forceinline__ float us2f(unsigned short s) {
    return __uint_as_float(((unsigned)s) << 16);
}
__device__ __forceinline__ short f2bs(float f) {
    bf16 b = __float2bfloat16(f);
    return *reinterpret_cast<short*>(&b);
}
__device__ __forceinline__ unsigned ford(float f) {
    unsigned u = __float_as_uint(f);
    return (u & 0x80000000u) ? ~u : (u | 0x80000000u);
}
__device__ __forceinline__ float iford(unsigned u) {
    return __uint_as_float((u & 0x80000000u) ? (u & 0x7fffffffu) : ~u);
}

// async global->LDS 16B; falls back to manual copy if builtin missing
__device__ __forceinline__ void g2l16(const void* g, void* l) {
#if __has_builtin(__builtin_amdgcn_global_load_lds)
    __builtin_amdgcn_global_load_lds((const __attribute__((address_space(1))) char*)g,
                                     (__attribute__((address_space(3))) char*)l, 16, 0, 0);
#else
    *(bf16x8*)l = *(const bf16x8*)g;
#endif
}

// G / GH2 layout: gate-interleaved  X[n*1536 + k*3 + g]; H1/h2: row-major [n][512]

// ---- K0: prep weights.
__global__ __launch_bounds__(256) void k_prep(const float* __restrict__ Whh,
                                              const float* __restrict__ Wih,
                                              bf16* __restrict__ WTs,
                                              float* __restrict__ WIT) {
    int t = blockIdx.x * 256 + threadIdx.x;   // 768 blocks -> 196608 exactly
    if (t < 98304) {
        int T = t >> 10, c = (t >> 6) & 15, l = t & 63;
        int n = T * 16 + (l & 15);
        int k = c * 32 + ((l >> 4) << 3);
        const float* src = Whh + (size_t)n * 512 + k;
        bf16x8 v;
#pragma unroll
        for (int j = 0; j < 8; ++j) v[j] = f2bs(src[j]);
        *(bf16x8*)(WTs + (size_t)t * 8) = v;
    } else {
        int u = t - 98304;          // WIT[d][j] = Wih[j][d]
        int d = u / 1536, j = u % 1536;
        WIT[u] = Wih[(size_t)j * 64 + d];
    }
}

// ---- CSR build: count / scan / fill
__global__ __launch_bounds__(256) void k_count(const int* __restrict__ dst,
                                               unsigned* __restrict__ cnt) {
    int e = blockIdx.x * 256 + threadIdx.x;
    if (e < N_EDGES) atomicAdd(&cnt[dst[e]], 1u);
}

#define SCAN_CH 79
__global__ __launch_bounds__(256) void k_scan(const unsigned* __restrict__ cnt,
                                              unsigned* __restrict__ base,
                                              unsigned* __restrict__ cursor) {
    __shared__ unsigned ls[256];
    int t = threadIdx.x;
    int s0 = t * SCAN_CH;
    int s1 = s0 + SCAN_CH < N_NODES ? s0 + SCAN_CH : N_NODES;
    unsigned s = 0;
    for (int i = s0; i < s1; ++i) s += cnt[i];
    ls[t] = s;
    __syncthreads();
    for (int d = 1; d < 256; d <<= 1) {
        unsigned v = (t >= d) ? ls[t - d] : 0u;
        __syncthreads();
        ls[t] += v;
        __syncthreads();
    }
    unsigned run = ls[t] - s;
    for (int i = s0; i < s1; ++i) {
        base[i] = run; cursor[i] = run; run += cnt[i];
    }
    if (t == 255) base[N_NODES] = ls[255];
}

__global__ __launch_bounds__(256) void k_fill(const int* __restrict__ dst,
                                              unsigned* __restrict__ cursor,
                                              unsigned* __restrict__ csr) {
    int e = blockIdx.x * 256 + threadIdx.x;
    if (e < N_EDGES) {
        unsigned p = atomicAdd(&cursor[dst[e]], 1u);
        csr[p] = (unsigned)e;
    }
}

// ---- K1: G[n][k][g] = features[n].W_ih + b_ih (interleaved); also H1[n][k] (free)
__global__ __launch_bounds__(256) void k_gi(const float* __restrict__ feat,
                                            const float* __restrict__ WIT,
                                            const float* __restrict__ b_ih,
                                            const float* __restrict__ b_hh,
                                            bf16* __restrict__ G,
                                            bf16* __restrict__ H1) {
    __shared__ float fs[16][64];
    const int n0 = blockIdx.x * 16;
    const int k = blockIdx.y * 256 + threadIdx.x;
    for (int i = threadIdx.x; i < 16 * 64; i += 256)
        fs[0][i] = feat[(size_t)n0 * 64 + i];
    __syncthreads();
    float acc[3][16];
#pragma unroll
    for (int g = 0; g < 3; ++g) {
        float b = b_ih[g * 512 + k];
#pragma unroll
        for (int e = 0; e < 16; ++e) acc[g][e] = b;
    }
    for (int d = 0; d < 64; d += 4) {
        float w[3][4];
#pragma unroll
        for (int u = 0; u < 4; ++u)
#pragma unroll
            for (int g = 0; g < 3; ++g)
                w[g][u] = WIT[(size_t)(d + u) * G3 + g * 512 + k];
#pragma unroll
        for (int e = 0; e < 16; ++e) {
            float4 f = *(const float4*)&fs[e][d];
#pragma unroll
            for (int g = 0; g < 3; ++g)
                acc[g][e] += w[g][0] * f.x + w[g][1] * f.y + w[g][2] * f.z + w[g][3] * f.w;
        }
    }
    const float br = b_hh[k], bz = b_hh[512 + k], bn = b_hh[1024 + k];
#pragma unroll
    for (int e = 0; e < 16; ++e) {
        bf16* dst = G + (size_t)(n0 + e) * G3 + k * 3;
        dst[0] = f2b(acc[0][e]);
        dst[1] = f2b(acc[1][e]);
        dst[2] = f2b(acc[2][e]);
        float r1 = fsig(acc[0][e] + br);
        float z1 = fsig(acc[1][e] + bz);
        float n1 = ftanh(acc[2][e] + r1 * bn);
        H1[(size_t)(n0 + e) * HID + k] = f2b((1.0f - z1) * n1);
    }
}

// ---- K2: GH2[n] = H1[n] @ W_hh^T + b_hh. M=128/block, A from H1 (contiguous).
__global__ __launch_bounds__(256, 2) void k_gh2(const bf16* __restrict__ H1,
                                                const bf16* __restrict__ WTs,
                                                const float* __restrict__ b_hh,
                                                bf16* __restrict__ GH2) {
    __shared__ short Bs[3 * 8192];   // 48 KB
    const int tid = threadIdx.x;
    const int wave = tid >> 6, lane = tid & 63;
    const int m0 = blockIdx.x * 128;
    const int k0 = (lane >> 4) << 3;

    bf16x8 afrag[2][16];
#pragma unroll
    for (int t = 0; t < 2; ++t) {
        int row = m0 + wave * 32 + t * 16 + (lane & 15);
        int ar = row < N_NODES ? row : N_NODES - 1;
#pragma unroll
        for (int c = 0; c < 16; ++c)
            afrag[t][c] = *(const bf16x8*)(H1 + (size_t)ar * HID + c * 32 + k0);
    }

    const bf16* wp[12];
    short* lp[12];
#pragma unroll
    for (int i = 0; i < 12; ++i) {
        int p = tid + i * 256;
        int g = p >> 10, q = p & 1023;
        wp[i] = WTs + (size_t)g * 32 * 8192 + q * 8;
        lp[i] = &Bs[g * 8192 + q * 8];
    }

    const int col = lane & 15;
    const int qb = (lane >> 4) << 2;
    for (int jt = 0; jt < 32; ++jt) {
        __syncthreads();
#pragma unroll
        for (int i = 0; i < 12; ++i) {
            g2l16(wp[i], lp[i]);
            wp[i] += 8192;
        }
        __syncthreads();
        f32x4 acc[2][3];
#pragma unroll
        for (int t = 0; t < 2; ++t)
#pragma unroll
            for (int g = 0; g < 3; ++g) acc[t][g] = (f32x4){0, 0, 0, 0};
        const int boff = lane * 8;
#pragma unroll
        for (int c = 0; c < 16; ++c) {
            bf16x8 b0 = *(const bf16x8*)&Bs[0 * 8192 + c * 512 + boff];
            bf16x8 b1 = *(const bf16x8*)&Bs[1 * 8192 + c * 512 + boff];
            bf16x8 b2 = *(const bf16x8*)&Bs[2 * 8192 + c * 512 + boff];
#pragma unroll
            for (int t = 0; t < 2; ++t) {
                acc[t][0] = __builtin_amdgcn_mfma_f32_16x16x32_bf16(afrag[t][c], b0, acc[t][0], 0, 0, 0);
                acc[t][1] = __builtin_amdgcn_mfma_f32_16x16x32_bf16(afrag[t][c], b1, acc[t][1], 0, 0, 0);
                acc[t][2] = __builtin_amdgcn_mfma_f32_16x16x32_bf16(afrag[t][c], b2, acc[t][2], 0, 0, 0);
            }
        }
        const int cj = jt * 16 + col;
        const float br = b_hh[cj], bz = b_hh[512 + cj], bn = b_hh[1024 + cj];
#pragma unroll
        for (int t = 0; t < 2; ++t)
#pragma unroll
            for (int q = 0; q < 4; ++q) {
                int e = m0 + wave * 32 + t * 16 + qb + q;
                if (e < N_NODES) {
                    bf16* dst = GH2 + (size_t)e * G3 + cj * 3;
                    dst[0] = f2b(acc[t][0][q] + br);
                    dst[1] = f2b(acc[t][1][q] + bz);
                    dst[2] = f2b(acc[t][2][q] + bn);
                }
            }
    }
}

// ---- K3: per-edge h2 = GRUstep2(G[i1], GH2[i0], H1[i0]) elementwise
__global__ __launch_bounds__(256) void k_h2(const bf16* __restrict__ G,
                                            const bf16* __restrict__ GH2,
                                            const bf16* __restrict__ H1,
                                            const int* __restrict__ emi,
                                            bf16* __restrict__ h2) {
    size_t i = (size_t)blockIdx.x * 256 + threadIdx.x;   // 25000 blocks exactly
    int e = (int)(i >> 6);
    int kc = (int)(i & 63) * 8;
    int i0 = emi[(size_t)e * 3 + 0];
    int i1 = emi[(size_t)e * 3 + 1];
    const bf16* g1p = G + (size_t)i1 * G3 + kc * 3;
    const bf16* ghp = GH2 + (size_t)i0 * G3 + kc * 3;
    bf16x8 h1v = *(const bf16x8*)(H1 + (size_t)i0 * HID + kc);
    short s1[24], sh[24];
    {
        bf16x8 a0 = *(const bf16x8*)g1p, a1 = *(const bf16x8*)(g1p + 8), a2 = *(const bf16x8*)(g1p + 16);
        bf16x8 c0 = *(const bf16x8*)ghp, c1 = *(const bf16x8*)(ghp + 8), c2 = *(const bf16x8*)(ghp + 16);
#pragma unroll
        for (int j = 0; j < 8; ++j) {
            s1[j] = a0[j]; s1[8 + j] = a1[j]; s1[16 + j] = a2[j];
            sh[j] = c0[j]; sh[8 + j] = c1[j]; sh[16 + j] = c2[j];
        }
    }
    bf16x8 out;
#pragma unroll
    for (int j = 0; j < 8; ++j) {
        float r = fsig(bs2f(s1[j * 3 + 0]) + bs2f(sh[j * 3 + 0]));
        float z = fsig(bs2f(s1[j * 3 + 1]) + bs2f(sh[j * 3 + 1]));
        float n = ftanh(bs2f(s1[j * 3 + 2]) + r * bs2f(sh[j * 3 + 2]));
        out[j] = f2bs((1.0f - z) * n + z * bs2f(h1v[j]));
    }
    *(bf16x8*)(h2 + (size_t)e * HID + kc) = out;
}

// ---- K4: gh3 = h2 @ W_hh^T; h3 = GRUstep3(G[i2], gh3+b_hh, h2) in-place.
// M=64/block (3 blocks/CU residency beats halved LDS traffic — measured r7 vs r8).
__global__ __launch_bounds__(256) void k_gemm3(const bf16* __restrict__ G,
                                               const bf16* __restrict__ WTs,
                                               const float* __restrict__ b_hh,
                                               const int* __restrict__ emi,
                                               bf16* __restrict__ h2) {
    __shared__ short Bs[3 * 8192];   // 48 KB
    __shared__ int si2[64];
    const int tid = threadIdx.x;
    const int wave = tid >> 6, lane = tid & 63;
    const int m0 = blockIdx.x * 64;
    if (tid < 64) {
        int e = m0 + tid;
        si2[tid] = emi[(size_t)(e < N_EDGES ? e : N_EDGES - 1) * 3 + 2];
    }
    const int k0 = (lane >> 4) << 3;

    // A frags: one 16-row m-tile per wave, full K in regs
    bf16x8 afrag[16];
    {
        int row = m0 + wave * 16 + (lane & 15);
        int ar = row < N_EDGES ? row : N_EDGES - 1;
#pragma unroll
        for (int c = 0; c < 16; ++c)
            afrag[c] = *(const bf16x8*)(h2 + (size_t)ar * HID + c * 32 + k0);
    }

    // hoisted staging pointers
    const bf16* wp[12];
    short* lp[12];
#pragma unroll
    for (int i = 0; i < 12; ++i) {
        int p = tid + i * 256;
        int g = p >> 10, q = p & 1023;
        wp[i] = WTs + (size_t)g * 32 * 8192 + q * 8;
        lp[i] = &Bs[g * 8192 + q * 8];
    }

    const int col = lane & 15;
    const int qb = (lane >> 4) << 2;
    for (int jt = 0; jt < 32; ++jt) {
        __syncthreads();
#pragma unroll
        for (int i = 0; i < 12; ++i) {
            g2l16(wp[i], lp[i]);
            wp[i] += 8192;
        }
        // prefetch epilogue operands (overlaps with staging + MFMA latency)
        const int cj = jt * 16 + col;
        const float br = b_hh[cj], bz = b_hh[512 + cj], bn = b_hh[1024 + cj];
        unsigned short pg[4][3], ph[4];
#pragma unroll
        for (int q = 0; q < 4; ++q) {
            int li = wave * 16 + qb + q;
            int e = m0 + li;
            int ec = e < N_EDGES ? e : N_EDGES - 1;
            const unsigned short* g2p =
                (const unsigned short*)(G + (size_t)si2[li] * G3 + cj * 3);
            pg[q][0] = g2p[0]; pg[q][1] = g2p[1]; pg[q][2] = g2p[2];
            ph[q] = ((const unsigned short*)h2)[(size_t)ec * HID + cj];
        }
        __syncthreads();
        f32x4 a0 = {0, 0, 0, 0}, a1 = {0, 0, 0, 0}, a2 = {0, 0, 0, 0};
        const int boff = lane * 8;
#pragma unroll
        for (int c = 0; c < 16; ++c) {
            bf16x8 b0 = *(const bf16x8*)&Bs[0 * 8192 + c * 512 + boff];
            bf16x8 b1 = *(const bf16x8*)&Bs[1 * 8192 + c * 512 + boff];
            bf16x8 b2 = *(const bf16x8*)&Bs[2 * 8192 + c * 512 + boff];
            a0 = __builtin_amdgcn_mfma_f32_16x16x32_bf16(afrag[c], b0, a0, 0, 0, 0);
            a1 = __builtin_amdgcn_mfma_f32_16x16x32_bf16(afrag[c], b1, a1, 0, 0, 0);
            a2 = __builtin_amdgcn_mfma_f32_16x16x32_bf16(afrag[c], b2, a2, 0, 0, 0);
        }
        // epilogue: pure compute + store (no loads)
#pragma unroll
        for (int q = 0; q < 4; ++q) {
            int e = m0 + wave * 16 + qb + q;
            if (e < N_EDGES) {
                float r = fsig(us2f(pg[q][0]) + a0[q] + br);
                float z = fsig(us2f(pg[q][1]) + a1[q] + bz);
                float ng = ftanh(us2f(pg[q][2]) + r * (a2[q] + bn));
                h2[(size_t)e * HID + cj] = f2b((1.0f - z) * ng + z * us2f(ph[q]));
            }
        }
    }
}

// ---- K6: attention logits + leaky relu + segment max
__global__ __launch_bounds__(256) void k_logits(const bf16* __restrict__ eft,
                                                const float* __restrict__ attn,
                                                const int* __restrict__ dst,
                                                float* __restrict__ a,
                                                unsigned* __restrict__ amax) {
    int i = blockIdx.x * 256 + threadIdx.x;  // E*NH exactly
    int e = i >> 3, h = i & 7;
    const __hip_bfloat162* f2 = (const __hip_bfloat162*)(eft + (size_t)e * HID + h * OD);
    const float* at = attn + h * OD;
    float s = 0.f;
#pragma unroll
    for (int d = 0; d < OD / 2; ++d) {
        float2 fv = __bfloat1622float2(f2[d]);
        s += fv.x * at[2 * d] + fv.y * at[2 * d + 1];
    }
    s = (s >= 0.f) ? s : 0.01f * s;
    a[i] = s;
    atomicMax(&amax[(size_t)dst[e] * NH + h], ford(s));
}

// ---- K7: ea = exp(a - amax[dst]); denom += ea
__global__ __launch_bounds__(256) void k_ea(const int* __restrict__ dst,
                                            const unsigned* __restrict__ amax,
                                            float* __restrict__ a,
                                            float* __restrict__ denom) {
    int i = blockIdx.x * 256 + threadIdx.x;
    int e = i >> 3, h = i & 7;
    float m = iford(amax[(size_t)dst[e] * NH + h]);
    float v = __expf(a[i] - m);
    a[i] = v;
    atomicAdd(&denom[(size_t)dst[e] * NH + h], v);
}

// ---- K8: out[n][k] = sum_e eft[e][k]*ea[e][h] / denom[n][h]   (CSR, no atomics)
__global__ __launch_bounds__(256) void k_out(const bf16* __restrict__ eft,
                                             const float* __restrict__ a,
                                             const float* __restrict__ denom,
                                             const unsigned* __restrict__ base,
                                             const unsigned* __restrict__ csr,
                                             float* __restrict__ out) {
    int n = blockIdx.x;
    int k = blockIdx.y * 256 + threadIdx.x;
    int h = k >> 6;
    unsigned b0 = base[n], b1 = base[n + 1];
    float rden = (b1 > b0) ? frcp(denom[(size_t)n * NH + h]) : 0.0f;
    float acc = 0.f;
    for (unsigned i = b0; i < b1; ++i) {
        unsigned e = csr[i];
        float al = a[(size_t)e * NH + h];
        acc += b2f(eft[(size_t)e * HID + k]) * al;
    }
    out[(size_t)n * HID + k] = acc * rden;
}

extern "C" void kernel_launch(void* const* d_in, const int* in_sizes, int n_in,
                              void* d_out, int out_size, void* d_ws, size_t ws_size,
                              hipStream_t stream) {
    (void)in_sizes; (void)n_in; (void)ws_size; (void)out_size;
    const float* feat = (const float*)d_in[0];
    const float* W_ih = (const float*)d_in[1];
    const float* W_hh = (const float*)d_in[2];
    const float* b_ih = (const float*)d_in[3];
    const float* b_hh = (const float*)d_in[4];
    const float* attn = (const float*)d_in[5];
    const int* emi = (const int*)d_in[6];
    const int* dst = (const int*)d_in[7];
    float* out = (float*)d_out;

    // workspace layout (bytes) — total ~252.8 MB (proven-safe)
    char* ws = (char*)d_ws;
    bf16* G = (bf16*)ws;                               // 61,440,000 B (interleaved)
    bf16* GH2 = (bf16*)(ws + 61440000);                // 61,440,000 B (interleaved)
    bf16* h2 = (bf16*)(ws + 122880000);                // 102,400,000 B (row-major; h3 in-place)
    bf16* WTs = (bf16*)(ws + 225280000);               // 1,572,864 B
    float* WIT = (float*)(ws + 226852864);             // 393,216 B
    float* a = (float*)(ws + 227246080);               // 3,200,000 B
    unsigned* amax = (unsigned*)(ws + 230446080);      // 640,000 B
    float* denom = (float*)(ws + 231086080);           // 640,000 B
    unsigned* cnt = (unsigned*)(ws + 231726080);       // 80,000 B
    unsigned* base = (unsigned*)(ws + 231806080);      // 80,008 B (20001 u32, pad)
    unsigned* cursor = (unsigned*)(ws + 231886088);    // 80,000 B
    unsigned* csr = (unsigned*)(ws + 231966088);       // 400,000 B
    bf16* H1 = (bf16*)(ws + 232366088);                // 20,480,000 B -> end 252,846,088

    // zero amax + denom + cnt (contiguous)
    (void)hipMemsetAsync(amax, 0, 1360000, stream);

    k_prep<<<768, 256, 0, stream>>>(W_hh, W_ih, WTs, WIT);
    k_count<<<391, 256, 0, stream>>>(dst, cnt);
    k_scan<<<1, 256, 0, stream>>>(cnt, base, cursor);
    k_fill<<<391, 256, 0, stream>>>(dst, cursor, csr);
    k_gi<<<dim3(1250, 2), 256, 0, stream>>>(feat, WIT, b_ih, b_hh, G, H1);
    k_gh2<<<157, 256, 0, stream>>>(H1, WTs, b_hh, GH2);
    k_h2<<<25000, 256, 0, stream>>>(G, GH2, H1, emi, h2);
    k_gemm3<<<1563, 256, 0, stream>>>(G, WTs, b_hh, emi, h2);
    k_logits<<<3125, 256, 0, stream>>>(h2, attn, dst, a, amax);
    k_ea<<<3125, 256, 0, stream>>>(dst, amax, a, denom);
    k_out<<<dim3(N_NODES, 2), 256, 0, stream>>>(h2, a, denom, base, csr, out);
}